// Round 4
// baseline (524.366 us; speedup 1.0000x reference)
//
#include <hip/hip_runtime.h>

#define CH 128
#define NCLS 16
#define CHK 16          // channels per chunk
#define NCHUNK 8        // 8 chunks of 16 == 128 channels, one per XCD
#define SCAN_IPB 1024   // items per block in scan pass 1

// ---------------------------------------------------------------- small utils
__global__ void zero_int_kernel(int* __restrict__ p, int n) {
    int i = blockIdx.x * blockDim.x + threadIdx.x;
    if (i < n) p[i] = 0;
}

__global__ void count_kernel(const int* __restrict__ dst,
                             int* __restrict__ cnt, int E) {
    int e = blockIdx.x * blockDim.x + threadIdx.x;
    if (e < E) atomicAdd(&cnt[dst[e]], 1);
}

__global__ void dis_kernel(const int* __restrict__ cnt,
                           float* __restrict__ dis, int n) {
    int i = blockIdx.x * blockDim.x + threadIdx.x;
    if (i < n) dis[i] = rsqrtf((float)cnt[i] + 1.0f);   // +1 = self-loop
}

// ---------------------------------------------------------------- scan (CSR)
__global__ __launch_bounds__(256) void scan1_kernel(
    const int* __restrict__ cnt, int* __restrict__ row_start,
    int* __restrict__ bsum, int n) {
    __shared__ int lds[256];
    int t = threadIdx.x, b = blockIdx.x;
    int base = b * SCAN_IPB + t * 4;
    int v[4];
    int s = 0;
#pragma unroll
    for (int k = 0; k < 4; k++) {
        v[k] = (base + k < n) ? cnt[base + k] : 0;
        s += v[k];
    }
    lds[t] = s;
    __syncthreads();
    for (int off = 1; off < 256; off <<= 1) {
        int x = (t >= off) ? lds[t - off] : 0;
        __syncthreads();
        lds[t] += x;
        __syncthreads();
    }
    int incl = lds[t];
    int run = incl - s;   // exclusive across threads
#pragma unroll
    for (int k = 0; k < 4; k++) {
        if (base + k < n) row_start[base + k] = run;
        run += v[k];
    }
    if (t == 255) bsum[b] = incl;
}

__global__ __launch_bounds__(256) void scan2_kernel(int* __restrict__ bsum, int nb) {
    __shared__ int lds[256];
    int t = threadIdx.x;
    int s = (t < nb) ? bsum[t] : 0;
    lds[t] = s;
    __syncthreads();
    for (int off = 1; off < 256; off <<= 1) {
        int x = (t >= off) ? lds[t - off] : 0;
        __syncthreads();
        lds[t] += x;
        __syncthreads();
    }
    if (t < nb) bsum[t] = lds[t] - s;   // exclusive
}

__global__ void scan3_kernel(int* __restrict__ row_start, int* __restrict__ cursor,
                             const int* __restrict__ bsum, int n, int E) {
    int i = blockIdx.x * blockDim.x + threadIdx.x;
    if (i < n) {
        int v = row_start[i] + bsum[i >> 10];   // >>10 == /SCAN_IPB
        row_start[i] = v;
        cursor[i] = v;
    }
    if (i == 0) row_start[n] = E;
}

__global__ void fill_kernel(const int* __restrict__ src, const int* __restrict__ dst,
                            int* __restrict__ cursor, int* __restrict__ esrc, int E) {
    int e = blockIdx.x * blockDim.x + threadIdx.x;
    if (e >= E) return;
    int p = atomicAdd(&cursor[dst[e]], 1);
    esrc[p] = src[e];
}

// ---------------------------------------------------------------- GEMM 128x128
// C is written CHUNK-MAJOR: C[chunk][row][16], chunk = col/16, and each row is
// PRE-SCALED by dis[row] (so the gather never touches dis[src]).
template <bool RELU_IN>
__global__ __launch_bounds__(256) void gemm_128_128(
    const float* __restrict__ A, const float* __restrict__ W,
    const float* __restrict__ dis, float* __restrict__ C, int n_rows) {
    __shared__ float As[64][33];
    __shared__ float Ws[32][132];

    const int tid = threadIdx.x;
    const int bm0 = blockIdx.x * 64;
    const int tc = tid & 31;
    const int tr = tid >> 5;

    float acc[8][4];
#pragma unroll
    for (int i = 0; i < 8; i++)
#pragma unroll
        for (int j = 0; j < 4; j++) acc[i][j] = 0.0f;

    for (int k0 = 0; k0 < 128; k0 += 32) {
#pragma unroll
        for (int i = 0; i < 8; i++) {
            int l = tid + i * 256;
            int r = l >> 5, c = l & 31;
            int gr = bm0 + r;
            float v = (gr < n_rows) ? A[(size_t)gr * CH + k0 + c] : 0.0f;
            if (RELU_IN) v = fmaxf(v, 0.0f);
            As[r][c] = v;
        }
#pragma unroll
        for (int i = 0; i < 16; i++) {
            int l = tid + i * 256;
            int r = l >> 7, c = l & 127;
            Ws[r][c] = W[(k0 + r) * CH + c];
        }
        __syncthreads();
#pragma unroll
        for (int kk = 0; kk < 32; kk++) {
            float4 b = *(const float4*)&Ws[kk][tc * 4];
            float a[8];
#pragma unroll
            for (int i = 0; i < 8; i++) a[i] = As[tr * 8 + i][kk];
#pragma unroll
            for (int i = 0; i < 8; i++) {
                acc[i][0] = fmaf(a[i], b.x, acc[i][0]);
                acc[i][1] = fmaf(a[i], b.y, acc[i][1]);
                acc[i][2] = fmaf(a[i], b.z, acc[i][2]);
                acc[i][3] = fmaf(a[i], b.w, acc[i][3]);
            }
        }
        __syncthreads();
    }
    const int chunk = tc >> 2;          // 16-channel chunk
    const int chOff = (tc & 3) * 4;     // float offset inside chunk
    float* __restrict__ Cc = C + (size_t)chunk * n_rows * CHK + chOff;
#pragma unroll
    for (int i = 0; i < 8; i++) {
        int gr = bm0 + tr * 8 + i;
        if (gr < n_rows) {
            float d = dis[gr];
            float4 v = make_float4(acc[i][0] * d, acc[i][1] * d,
                                   acc[i][2] * d, acc[i][3] * d);
            *(float4*)&Cc[(size_t)gr * CHK] = v;
        }
    }
}

// ---------------------------------------------------------------- CSR gather
// wave per (node, chunk); chunk = blockIdx%8 tracks the XCD (round-robin
// dispatch heuristic) so each XCD's 3.2MB chunk slice stays L2-resident.
// hC is chunk-major and pre-scaled by dis[row]:
//   out[i, c*16+ch] = bias + dis[i] * ( hC[c][i][ch] + sum_e hC[c][esrc][ch] )
// lane = slot*16+ch: 4 edge slots x 16 channels, shfl_xor reduce over slots.
__global__ __launch_bounds__(256) void gather_kernel(
    const int* __restrict__ row_start, const int* __restrict__ esrc,
    const float* __restrict__ dis, const float* __restrict__ hC,
    const float* __restrict__ bias, float* __restrict__ out, int n) {
    int c = blockIdx.x & 7;
    int nodeBlk = blockIdx.x >> 3;
    int wv = threadIdx.x >> 6;
    int lane = threadIdx.x & 63;
    int i = nodeBlk * 4 + wv;
    if (i >= n) return;
    int slot = lane >> 4, ch = lane & 15;
    const float* __restrict__ hc = hC + (size_t)c * n * CHK;

    float acc = 0.0f;
    int beg = row_start[i], end = row_start[i + 1];
    for (int j = beg + slot; j < end; j += 8) {
        int j2 = j + 4;
        bool v1 = (j2 < end);
        int s0 = esrc[j];
        int s1 = v1 ? esrc[j2] : 0;
        float m1 = v1 ? 1.0f : 0.0f;
        float h0 = hc[(size_t)s0 * CHK + ch];
        float h1 = hc[(size_t)s1 * CHK + ch];
        acc += h0;
        acc = fmaf(m1, h1, acc);
    }
    acc += __shfl_xor(acc, 16);
    acc += __shfl_xor(acc, 32);
    if (slot == 0) {
        float di = dis[i];
        float hself = hc[(size_t)i * CHK + ch];
        out[(size_t)i * CH + c * CHK + ch] =
            bias[c * CHK + ch] + di * (acc + hself);
    }
}

// ---------------------------------------------------------------- head
__global__ __launch_bounds__(256) void head_kernel(
    const float* __restrict__ A, const float* __restrict__ Wh,
    const float* __restrict__ bh, float* __restrict__ out, int n) {
    __shared__ float Ws[CH * NCLS];
    __shared__ float As[16][129];
    const int tid = threadIdx.x;
    const int n0 = blockIdx.x * 16;
#pragma unroll
    for (int i = 0; i < 8; i++) {
        int l = tid + i * 256;
        Ws[l] = Wh[l];
    }
#pragma unroll
    for (int i = 0; i < 8; i++) {
        int l = tid + i * 256;
        int r = l >> 7, c = l & 127;
        int gr = n0 + r;
        As[r][c] = (gr < n) ? fmaxf(A[(size_t)gr * CH + c], 0.0f) : 0.0f;
    }
    __syncthreads();
    int r = tid >> 4, c = tid & 15;
    float acc = bh[c];
#pragma unroll
    for (int k = 0; k < CH; k++) acc = fmaf(As[r][k], Ws[k * NCLS + c], acc);
    int gr = n0 + r;
    if (gr < n) out[(size_t)gr * NCLS + c] = acc;
}

// ---------------------------------------------------------------- launch
extern "C" void kernel_launch(void* const* d_in, const int* in_sizes, int n_in,
                              void* d_out, int out_size, void* d_ws, size_t ws_size,
                              hipStream_t stream) {
    const float* x  = (const float*)d_in[0];
    const int*   ei = (const int*)d_in[1];
    const float* W1 = (const float*)d_in[2];
    const float* b1 = (const float*)d_in[3];
    const float* W2 = (const float*)d_in[4];
    const float* b2 = (const float*)d_in[5];
    const float* Wh = (const float*)d_in[6];
    const float* bh = (const float*)d_in[7];
    float* out = (float*)d_out;

    const int n = in_sizes[0] / CH;   // 50000
    const int E = in_sizes[1] / 2;    // 800000
    const int* src = ei;
    const int* dst = ei + E;

    // workspace layout (floats first for 16B alignment)
    float* dis  = (float*)d_ws;                 // n floats
    float* bufA = dis + n;                      // n*128 (chunk-major h')
    float* bufB = bufA + (size_t)n * CH;        // n*128 (row-major gather out)
    int* cnt       = (int*)(bufB + (size_t)n * CH);  // n
    int* row_start = cnt + n;                   // n+1
    int* cursor    = row_start + n + 1;         // n
    int* bsum      = cursor + n;                // up to 256
    int* esrc      = bsum + 256;                // E

    const int B = 256;
    const int nb_scan = (n + SCAN_IPB - 1) / SCAN_IPB;   // 49

    // ---- CSR build + normalization (once, reused by both layers)
    zero_int_kernel<<<(n + B - 1) / B, B, 0, stream>>>(cnt, n);
    count_kernel<<<(E + B - 1) / B, B, 0, stream>>>(dst, cnt, E);
    dis_kernel<<<(n + B - 1) / B, B, 0, stream>>>(cnt, dis, n);
    scan1_kernel<<<nb_scan, B, 0, stream>>>(cnt, row_start, bsum, n);
    scan2_kernel<<<1, B, 0, stream>>>(bsum, nb_scan);
    scan3_kernel<<<(n + B - 1) / B, B, 0, stream>>>(row_start, cursor, bsum, n, E);
    fill_kernel<<<(E + B - 1) / B, B, 0, stream>>>(src, dst, cursor, esrc, E);

    const int gemmGrid = (n + 63) / 64;
    const int gatherGrid = NCHUNK * ((n + 3) / 4);   // (chunk, 4 nodes) per block

    // layer 1
    gemm_128_128<false><<<gemmGrid, B, 0, stream>>>(x, W1, dis, bufA, n);
    gather_kernel<<<gatherGrid, B, 0, stream>>>(row_start, esrc, dis, bufA, b1, bufB, n);
    // layer 2
    gemm_128_128<true><<<gemmGrid, B, 0, stream>>>(bufB, W2, dis, bufA, n);
    gather_kernel<<<gatherGrid, B, 0, stream>>>(row_start, esrc, dis, bufA, b2, bufB, n);
    // head
    head_kernel<<<(n + 15) / 16, B, 0, stream>>>(bufB, Wh, bh, out, n);
}

// Round 5
// 499.622 us; speedup vs baseline: 1.0495x; 1.0495x over previous
//
#include <hip/hip_runtime.h>

#define CH 128
#define NCLS 16
#define CHK 16          // channels per chunk
#define NCHUNK 8        // 8 chunks of 16 == 128 channels, one per XCD
#define SCAN_IPB 1024   // items per block in scan pass 1

// ---------------------------------------------------------------- small utils
__global__ void zero_int_kernel(int* __restrict__ p, int n) {
    int i = blockIdx.x * blockDim.x + threadIdx.x;
    if (i < n) p[i] = 0;
}

__global__ void count_kernel(const int* __restrict__ dst,
                             int* __restrict__ cnt, int E) {
    int e = blockIdx.x * blockDim.x + threadIdx.x;
    if (e < E) atomicAdd(&cnt[dst[e]], 1);
}

__global__ void dis_kernel(const int* __restrict__ cnt,
                           float* __restrict__ dis, int n) {
    int i = blockIdx.x * blockDim.x + threadIdx.x;
    if (i < n) dis[i] = rsqrtf((float)cnt[i] + 1.0f);   // +1 = self-loop
}

// ---------------------------------------------------------------- scan (CSR)
__global__ __launch_bounds__(256) void scan1_kernel(
    const int* __restrict__ cnt, int* __restrict__ row_start,
    int* __restrict__ bsum, int n) {
    __shared__ int lds[256];
    int t = threadIdx.x, b = blockIdx.x;
    int base = b * SCAN_IPB + t * 4;
    int v[4];
    int s = 0;
#pragma unroll
    for (int k = 0; k < 4; k++) {
        v[k] = (base + k < n) ? cnt[base + k] : 0;
        s += v[k];
    }
    lds[t] = s;
    __syncthreads();
    for (int off = 1; off < 256; off <<= 1) {
        int x = (t >= off) ? lds[t - off] : 0;
        __syncthreads();
        lds[t] += x;
        __syncthreads();
    }
    int incl = lds[t];
    int run = incl - s;   // exclusive across threads
#pragma unroll
    for (int k = 0; k < 4; k++) {
        if (base + k < n) row_start[base + k] = run;
        run += v[k];
    }
    if (t == 255) bsum[b] = incl;
}

__global__ __launch_bounds__(256) void scan2_kernel(int* __restrict__ bsum, int nb) {
    __shared__ int lds[256];
    int t = threadIdx.x;
    int s = (t < nb) ? bsum[t] : 0;
    lds[t] = s;
    __syncthreads();
    for (int off = 1; off < 256; off <<= 1) {
        int x = (t >= off) ? lds[t - off] : 0;
        __syncthreads();
        lds[t] += x;
        __syncthreads();
    }
    if (t < nb) bsum[t] = lds[t] - s;   // exclusive
}

__global__ void scan3_kernel(int* __restrict__ row_start, int* __restrict__ cursor,
                             const int* __restrict__ bsum, int n, int E) {
    int i = blockIdx.x * blockDim.x + threadIdx.x;
    if (i < n) {
        int v = row_start[i] + bsum[i >> 10];   // >>10 == /SCAN_IPB
        row_start[i] = v;
        cursor[i] = v;
    }
    if (i == 0) row_start[n] = E;
}

__global__ void fill_kernel(const int* __restrict__ src, const int* __restrict__ dst,
                            int* __restrict__ cursor, int* __restrict__ esrc, int E) {
    int e = blockIdx.x * blockDim.x + threadIdx.x;
    if (e >= E) return;
    int p = atomicAdd(&cursor[dst[e]], 1);
    esrc[p] = src[e];
}

// ---------------------------------------------------------------- GEMM 128x128
// C is written CHUNK-MAJOR: C[chunk][row][16], chunk = col/16, and each row is
// PRE-SCALED by dis[row] (so the gather never touches dis[src]).
template <bool RELU_IN>
__global__ __launch_bounds__(256) void gemm_128_128(
    const float* __restrict__ A, const float* __restrict__ W,
    const float* __restrict__ dis, float* __restrict__ C, int n_rows) {
    __shared__ float As[64][33];
    __shared__ float Ws[32][132];

    const int tid = threadIdx.x;
    const int bm0 = blockIdx.x * 64;
    const int tc = tid & 31;
    const int tr = tid >> 5;

    float acc[8][4];
#pragma unroll
    for (int i = 0; i < 8; i++)
#pragma unroll
        for (int j = 0; j < 4; j++) acc[i][j] = 0.0f;

    for (int k0 = 0; k0 < 128; k0 += 32) {
#pragma unroll
        for (int i = 0; i < 8; i++) {
            int l = tid + i * 256;
            int r = l >> 5, c = l & 31;
            int gr = bm0 + r;
            float v = (gr < n_rows) ? A[(size_t)gr * CH + k0 + c] : 0.0f;
            if (RELU_IN) v = fmaxf(v, 0.0f);
            As[r][c] = v;
        }
#pragma unroll
        for (int i = 0; i < 16; i++) {
            int l = tid + i * 256;
            int r = l >> 7, c = l & 127;
            Ws[r][c] = W[(k0 + r) * CH + c];
        }
        __syncthreads();
#pragma unroll
        for (int kk = 0; kk < 32; kk++) {
            float4 b = *(const float4*)&Ws[kk][tc * 4];
            float a[8];
#pragma unroll
            for (int i = 0; i < 8; i++) a[i] = As[tr * 8 + i][kk];
#pragma unroll
            for (int i = 0; i < 8; i++) {
                acc[i][0] = fmaf(a[i], b.x, acc[i][0]);
                acc[i][1] = fmaf(a[i], b.y, acc[i][1]);
                acc[i][2] = fmaf(a[i], b.z, acc[i][2]);
                acc[i][3] = fmaf(a[i], b.w, acc[i][3]);
            }
        }
        __syncthreads();
    }
    const int chunk = tc >> 2;          // 16-channel chunk
    const int chOff = (tc & 3) * 4;     // float offset inside chunk
    float* __restrict__ Cc = C + (size_t)chunk * n_rows * CHK + chOff;
#pragma unroll
    for (int i = 0; i < 8; i++) {
        int gr = bm0 + tr * 8 + i;
        if (gr < n_rows) {
            float d = dis[gr];
            float4 v = make_float4(acc[i][0] * d, acc[i][1] * d,
                                   acc[i][2] * d, acc[i][3] * d);
            *(float4*)&Cc[(size_t)gr * CHK] = v;
        }
    }
}

// ---------------------------------------------------------------- CSR gather
// wave per (node, chunk); chunk = blockIdx%8 tracks the XCD so each XCD's
// 3.2MB chunk slice stays L2-resident (proven by FETCH_SIZE in round 4).
// Lane layout: eg = lane>>2 (16 edge slots), cq = lane&3 (float4 in 64B row).
// One float4 load-issue covers 16 edges -> 16 full cache lines, no waste.
// hC is chunk-major, rows pre-scaled by dis[row]:
//   out[i, c*16+:16] = bias + dis[i] * ( hC[c][i] + sum_e hC[c][esrc[e]] )
__global__ __launch_bounds__(256) void gather_kernel(
    const int* __restrict__ row_start, const int* __restrict__ esrc,
    const float* __restrict__ dis, const float* __restrict__ hC,
    const float* __restrict__ bias, float* __restrict__ out, int n) {
    int c = blockIdx.x & 7;
    int nodeBlk = blockIdx.x >> 3;
    int wv = threadIdx.x >> 6;
    int lane = threadIdx.x & 63;
    int i = nodeBlk * 4 + wv;
    if (i >= n) return;
    int eg = lane >> 2;   // edge slot 0..15
    int cq = lane & 3;    // float4 group within the 16-channel row
    const float4* __restrict__ h4 = (const float4*)(hC + (size_t)c * n * CHK);

    float4 acc = make_float4(0.f, 0.f, 0.f, 0.f);
    int beg = row_start[i], end = row_start[i + 1];
    for (int j0 = beg; j0 < end; j0 += 64) {
        int jl = j0 + lane;
        int sidx = 0;
        float msk = 0.0f;
        if (jl < end) { sidx = esrc[jl]; msk = 1.0f; }
        int m = min(64, end - j0);
        int steps = (m + 15) >> 4;
        for (int t = 0; t < steps; t++) {
            int sj = __shfl(sidx, t * 16 + eg);
            float mj = __shfl(msk, t * 16 + eg);
            float4 hv = h4[(size_t)sj * 4 + cq];
            acc.x = fmaf(mj, hv.x, acc.x);
            acc.y = fmaf(mj, hv.y, acc.y);
            acc.z = fmaf(mj, hv.z, acc.z);
            acc.w = fmaf(mj, hv.w, acc.w);
        }
    }
    // reduce the 16 edge slots (xor over lane bits 2..5)
#pragma unroll
    for (int off = 4; off < 64; off <<= 1) {
        acc.x += __shfl_xor(acc.x, off);
        acc.y += __shfl_xor(acc.y, off);
        acc.z += __shfl_xor(acc.z, off);
        acc.w += __shfl_xor(acc.w, off);
    }
    if (eg == 0) {
        float di = dis[i];
        float4 hs = h4[(size_t)i * 4 + cq];
        float4 bv = ((const float4*)bias)[c * 4 + cq];
        float4 o;
        o.x = bv.x + di * (acc.x + hs.x);
        o.y = bv.y + di * (acc.y + hs.y);
        o.z = bv.z + di * (acc.z + hs.z);
        o.w = bv.w + di * (acc.w + hs.w);
        ((float4*)out)[(size_t)i * 32 + c * 4 + cq] = o;
    }
}

// ---------------------------------------------------------------- head
__global__ __launch_bounds__(256) void head_kernel(
    const float* __restrict__ A, const float* __restrict__ Wh,
    const float* __restrict__ bh, float* __restrict__ out, int n) {
    __shared__ float Ws[CH * NCLS];
    __shared__ float As[16][129];
    const int tid = threadIdx.x;
    const int n0 = blockIdx.x * 16;
#pragma unroll
    for (int i = 0; i < 8; i++) {
        int l = tid + i * 256;
        Ws[l] = Wh[l];
    }
#pragma unroll
    for (int i = 0; i < 8; i++) {
        int l = tid + i * 256;
        int r = l >> 7, c = l & 127;
        int gr = n0 + r;
        As[r][c] = (gr < n) ? fmaxf(A[(size_t)gr * CH + c], 0.0f) : 0.0f;
    }
    __syncthreads();
    int r = tid >> 4, c = tid & 15;
    float acc = bh[c];
#pragma unroll
    for (int k = 0; k < CH; k++) acc = fmaf(As[r][k], Ws[k * NCLS + c], acc);
    int gr = n0 + r;
    if (gr < n) out[(size_t)gr * NCLS + c] = acc;
}

// ---------------------------------------------------------------- launch
extern "C" void kernel_launch(void* const* d_in, const int* in_sizes, int n_in,
                              void* d_out, int out_size, void* d_ws, size_t ws_size,
                              hipStream_t stream) {
    const float* x  = (const float*)d_in[0];
    const int*   ei = (const int*)d_in[1];
    const float* W1 = (const float*)d_in[2];
    const float* b1 = (const float*)d_in[3];
    const float* W2 = (const float*)d_in[4];
    const float* b2 = (const float*)d_in[5];
    const float* Wh = (const float*)d_in[6];
    const float* bh = (const float*)d_in[7];
    float* out = (float*)d_out;

    const int n = in_sizes[0] / CH;   // 50000
    const int E = in_sizes[1] / 2;    // 800000
    const int* src = ei;
    const int* dst = ei + E;

    // workspace layout (floats first for 16B alignment)
    float* dis  = (float*)d_ws;                 // n floats
    float* bufA = dis + n;                      // n*128 (chunk-major h')
    float* bufB = bufA + (size_t)n * CH;        // n*128 (row-major gather out)
    int* cnt       = (int*)(bufB + (size_t)n * CH);  // n
    int* row_start = cnt + n;                   // n+1
    int* cursor    = row_start + n + 1;         // n
    int* bsum      = cursor + n;                // up to 256
    int* esrc      = bsum + 256;                // E

    const int B = 256;
    const int nb_scan = (n + SCAN_IPB - 1) / SCAN_IPB;   // 49

    // ---- CSR build + normalization (once, reused by both layers)
    zero_int_kernel<<<(n + B - 1) / B, B, 0, stream>>>(cnt, n);
    count_kernel<<<(E + B - 1) / B, B, 0, stream>>>(dst, cnt, E);
    dis_kernel<<<(n + B - 1) / B, B, 0, stream>>>(cnt, dis, n);
    scan1_kernel<<<nb_scan, B, 0, stream>>>(cnt, row_start, bsum, n);
    scan2_kernel<<<1, B, 0, stream>>>(bsum, nb_scan);
    scan3_kernel<<<(n + B - 1) / B, B, 0, stream>>>(row_start, cursor, bsum, n, E);
    fill_kernel<<<(E + B - 1) / B, B, 0, stream>>>(src, dst, cursor, esrc, E);

    const int gemmGrid = (n + 63) / 64;
    const int gatherGrid = NCHUNK * ((n + 3) / 4);   // (chunk, 4 nodes) per block

    // layer 1
    gemm_128_128<false><<<gemmGrid, B, 0, stream>>>(x, W1, dis, bufA, n);
    gather_kernel<<<gatherGrid, B, 0, stream>>>(row_start, esrc, dis, bufA, b1, bufB, n);
    // layer 2
    gemm_128_128<true><<<gemmGrid, B, 0, stream>>>(bufB, W2, dis, bufA, n);
    gather_kernel<<<gatherGrid, B, 0, stream>>>(row_start, esrc, dis, bufA, b2, bufB, n);
    // head
    head_kernel<<<(n + 15) / 16, B, 0, stream>>>(bufB, Wh, bh, out, n);
}

// Round 6
// 489.073 us; speedup vs baseline: 1.0722x; 1.0216x over previous
//
#include <hip/hip_runtime.h>

#define CH 128
#define NCLS 16
#define CHK 16          // channels per chunk
#define NCHUNK 8        // 8 chunks of 16 == 128 channels, one per XCD
#define SCAN_IPB 1024   // items per block in scan pass 1

// ---------------------------------------------------------------- small utils
__global__ void zero_int_kernel(int* __restrict__ p, int n) {
    int i = blockIdx.x * blockDim.x + threadIdx.x;
    if (i < n) p[i] = 0;
}

__global__ void count_kernel(const int* __restrict__ dst,
                             int* __restrict__ cnt, int E) {
    int e = blockIdx.x * blockDim.x + threadIdx.x;
    if (e < E) atomicAdd(&cnt[dst[e]], 1);
}

__global__ void dis_kernel(const int* __restrict__ cnt,
                           float* __restrict__ dis, int n) {
    int i = blockIdx.x * blockDim.x + threadIdx.x;
    if (i < n) dis[i] = rsqrtf((float)cnt[i] + 1.0f);   // +1 = self-loop
}

// zero the dummy row (index n) of the chunk-major h buffer
__global__ void zero_row_kernel(float* __restrict__ hC, int n) {
    int t = threadIdx.x;          // 128 threads
    int c = t >> 4, ch = t & 15;
    hC[(size_t)c * (n + 1) * CHK + (size_t)n * CHK + ch] = 0.0f;
}

// ---------------------------------------------------------------- scan (CSR)
// scan over PADDED counts: pc[i] = round8(cnt[i] + 1)  (self-loop + pad-to-8)
__global__ __launch_bounds__(256) void scan1_kernel(
    const int* __restrict__ cnt, int* __restrict__ rsp,
    int* __restrict__ bsum, int n) {
    __shared__ int lds[256];
    int t = threadIdx.x, b = blockIdx.x;
    int base = b * SCAN_IPB + t * 4;
    int v[4];
    int s = 0;
#pragma unroll
    for (int k = 0; k < 4; k++) {
        v[k] = (base + k < n) ? ((cnt[base + k] + 8) & ~7) : 0;
        s += v[k];
    }
    lds[t] = s;
    __syncthreads();
    for (int off = 1; off < 256; off <<= 1) {
        int x = (t >= off) ? lds[t - off] : 0;
        __syncthreads();
        lds[t] += x;
        __syncthreads();
    }
    int incl = lds[t];
    int run = incl - s;   // exclusive across threads
#pragma unroll
    for (int k = 0; k < 4; k++) {
        if (base + k < n) rsp[base + k] = run;
        run += v[k];
    }
    if (t == 255) bsum[b] = incl;
}

__global__ __launch_bounds__(256) void scan2_kernel(int* __restrict__ bsum, int nb) {
    __shared__ int lds[256];
    int t = threadIdx.x;
    int s = (t < nb) ? bsum[t] : 0;
    lds[t] = s;
    __syncthreads();
    for (int off = 1; off < 256; off <<= 1) {
        int x = (t >= off) ? lds[t - off] : 0;
        __syncthreads();
        lds[t] += x;
        __syncthreads();
    }
    if (t < nb) bsum[t] = lds[t] - s;   // exclusive
}

// finalize rsp, init cursor, write self-edge and pad entries (dummy row n)
__global__ void scan3_kernel(int* __restrict__ rsp, int* __restrict__ cursor,
                             const int* __restrict__ bsum,
                             const int* __restrict__ cnt,
                             int* __restrict__ esrc, int n) {
    int i = blockIdx.x * blockDim.x + threadIdx.x;
    if (i >= n) return;
    int v = rsp[i] + bsum[i >> 10];   // >>10 == /SCAN_IPB
    rsp[i] = v;
    cursor[i] = v + 1;                // slot v holds the self-edge
    esrc[v] = i;                      // self-loop as a real edge
    int ci = cnt[i];
    int pc = (ci + 8) & ~7;
    for (int p = v + 1 + ci; p < v + pc; p++) esrc[p] = n;  // pads -> zero row
    if (i == n - 1) rsp[n] = v + pc;
}

__global__ void fill_kernel(const int* __restrict__ src, const int* __restrict__ dst,
                            int* __restrict__ cursor, int* __restrict__ esrc, int E) {
    int e = blockIdx.x * blockDim.x + threadIdx.x;
    if (e >= E) return;
    int p = atomicAdd(&cursor[dst[e]], 1);
    esrc[p] = src[e];
}

// ---------------------------------------------------------------- GEMM 128x128
// C is CHUNK-MAJOR with a dummy row: C[chunk][(n_rows+1)][16], chunk = col/16,
// each row PRE-SCALED by dis[row] (gather never touches dis[src]).
template <bool RELU_IN>
__global__ __launch_bounds__(256) void gemm_128_128(
    const float* __restrict__ A, const float* __restrict__ W,
    const float* __restrict__ dis, float* __restrict__ C, int n_rows) {
    __shared__ float As[64][33];
    __shared__ float Ws[32][132];

    const int tid = threadIdx.x;
    const int bm0 = blockIdx.x * 64;
    const int tc = tid & 31;
    const int tr = tid >> 5;

    float acc[8][4];
#pragma unroll
    for (int i = 0; i < 8; i++)
#pragma unroll
        for (int j = 0; j < 4; j++) acc[i][j] = 0.0f;

    for (int k0 = 0; k0 < 128; k0 += 32) {
#pragma unroll
        for (int i = 0; i < 8; i++) {
            int l = tid + i * 256;
            int r = l >> 5, c = l & 31;
            int gr = bm0 + r;
            float v = (gr < n_rows) ? A[(size_t)gr * CH + k0 + c] : 0.0f;
            if (RELU_IN) v = fmaxf(v, 0.0f);
            As[r][c] = v;
        }
#pragma unroll
        for (int i = 0; i < 16; i++) {
            int l = tid + i * 256;
            int r = l >> 7, c = l & 127;
            Ws[r][c] = W[(k0 + r) * CH + c];
        }
        __syncthreads();
#pragma unroll
        for (int kk = 0; kk < 32; kk++) {
            float4 b = *(const float4*)&Ws[kk][tc * 4];
            float a[8];
#pragma unroll
            for (int i = 0; i < 8; i++) a[i] = As[tr * 8 + i][kk];
#pragma unroll
            for (int i = 0; i < 8; i++) {
                acc[i][0] = fmaf(a[i], b.x, acc[i][0]);
                acc[i][1] = fmaf(a[i], b.y, acc[i][1]);
                acc[i][2] = fmaf(a[i], b.z, acc[i][2]);
                acc[i][3] = fmaf(a[i], b.w, acc[i][3]);
            }
        }
        __syncthreads();
    }
    const int chunk = tc >> 2;          // 16-channel chunk
    const int chOff = (tc & 3) * 4;     // float offset inside chunk
    float* __restrict__ Cc = C + (size_t)chunk * (n_rows + 1) * CHK + chOff;
#pragma unroll
    for (int i = 0; i < 8; i++) {
        int gr = bm0 + tr * 8 + i;
        if (gr < n_rows) {
            float d = dis[gr];
            float4 v = make_float4(acc[i][0] * d, acc[i][1] * d,
                                   acc[i][2] * d, acc[i][3] * d);
            *(float4*)&Cc[(size_t)gr * CHK] = v;
        }
    }
}

// ---------------------------------------------------------------- CSR gather
// wave per (node, chunk); chunk = blockIdx%8 pins the 3.2MB slice per XCD.
// Edge lists padded to x8 (pads -> zero row n), self-loop included as edge.
// Lane = (eg = lane>>3 edge slot, c2 = lane&7 float2 in the 64B row):
// one float2 wave-load covers 8 full rows; esrc loaded directly (no shfl).
//   out[i, c*16+:16] = bias + dis[i] * sum_slots hC[c][esrc[slot]]
__global__ __launch_bounds__(256) void gather_kernel(
    const int* __restrict__ rsp, const int* __restrict__ esrc,
    const float* __restrict__ dis, const float* __restrict__ hC,
    const float* __restrict__ bias, float* __restrict__ out, int n) {
    int c = blockIdx.x & 7;
    int nodeBlk = blockIdx.x >> 3;
    int i = nodeBlk * 4 + (threadIdx.x >> 6);
    if (i >= n) return;
    i = __builtin_amdgcn_readfirstlane(i);   // scalarize row bounds
    int lane = threadIdx.x & 63;
    int eg = lane >> 3;   // edge slot 0..7
    int c2 = lane & 7;    // float2 within the 16-channel row
    const float2* __restrict__ h2 =
        (const float2*)(hC + (size_t)c * (n + 1) * CHK);

    int beg = rsp[i], end = rsp[i + 1];
    float ax = 0.f, ay = 0.f;
    int j = beg;
    for (; j + 16 <= end; j += 16) {          // unroll-2: two chains in flight
        int s0 = esrc[j + eg];
        int s1 = esrc[j + 8 + eg];
        float2 a = h2[(size_t)s0 * 8 + c2];
        float2 b = h2[(size_t)s1 * 8 + c2];
        ax += a.x; ay += a.y;
        ax += b.x; ay += b.y;
    }
    if (j < end) {
        int s0 = esrc[j + eg];
        float2 a = h2[(size_t)s0 * 8 + c2];
        ax += a.x; ay += a.y;
    }
    // reduce the 8 edge slots (xor over lane bits 3..5)
#pragma unroll
    for (int off = 8; off < 64; off <<= 1) {
        ax += __shfl_xor(ax, off);
        ay += __shfl_xor(ay, off);
    }
    if (eg == 0) {
        float di = dis[i];
        float2 bv = ((const float2*)bias)[c * 8 + c2];
        float2 o = make_float2(bv.x + di * ax, bv.y + di * ay);
        ((float2*)out)[(size_t)i * 64 + c * 8 + c2] = o;
    }
}

// ---------------------------------------------------------------- head
__global__ __launch_bounds__(256) void head_kernel(
    const float* __restrict__ A, const float* __restrict__ Wh,
    const float* __restrict__ bh, float* __restrict__ out, int n) {
    __shared__ float Ws[CH * NCLS];
    __shared__ float As[16][129];
    const int tid = threadIdx.x;
    const int n0 = blockIdx.x * 16;
#pragma unroll
    for (int i = 0; i < 8; i++) {
        int l = tid + i * 256;
        Ws[l] = Wh[l];
    }
#pragma unroll
    for (int i = 0; i < 8; i++) {
        int l = tid + i * 256;
        int r = l >> 7, c = l & 127;
        int gr = n0 + r;
        As[r][c] = (gr < n) ? fmaxf(A[(size_t)gr * CH + c], 0.0f) : 0.0f;
    }
    __syncthreads();
    int r = tid >> 4, c = tid & 15;
    float acc = bh[c];
#pragma unroll
    for (int k = 0; k < CH; k++) acc = fmaf(As[r][k], Ws[k * NCLS + c], acc);
    int gr = n0 + r;
    if (gr < n) out[(size_t)gr * NCLS + c] = acc;
}

// ---------------------------------------------------------------- launch
extern "C" void kernel_launch(void* const* d_in, const int* in_sizes, int n_in,
                              void* d_out, int out_size, void* d_ws, size_t ws_size,
                              hipStream_t stream) {
    const float* x  = (const float*)d_in[0];
    const int*   ei = (const int*)d_in[1];
    const float* W1 = (const float*)d_in[2];
    const float* b1 = (const float*)d_in[3];
    const float* W2 = (const float*)d_in[4];
    const float* b2 = (const float*)d_in[5];
    const float* Wh = (const float*)d_in[6];
    const float* bh = (const float*)d_in[7];
    float* out = (float*)d_out;

    const int n = in_sizes[0] / CH;   // 50000
    const int E = in_sizes[1] / 2;    // 800000
    const int* src = ei;
    const int* dst = ei + E;

    // workspace layout
    float* dis  = (float*)d_ws;                      // n
    float* bufA = dis + n;                           // (n+1)*128  chunk-major h'
    float* bufB = bufA + (size_t)(n + 1) * CH;       // n*128      row-major
    int* cnt    = (int*)(bufB + (size_t)n * CH);     // n
    int* rsp    = cnt + n;                           // n+1 (padded CSR starts)
    int* cursor = rsp + n + 1;                       // n
    int* bsum   = cursor + n;                        // up to 256
    int* esrc   = bsum + 256;                        // E + 8n (padded edges)

    const int B = 256;
    const int nb_scan = (n + SCAN_IPB - 1) / SCAN_IPB;   // 49

    // ---- CSR build (padded, self-loops embedded) + normalization
    zero_int_kernel<<<(n + B - 1) / B, B, 0, stream>>>(cnt, n);
    count_kernel<<<(E + B - 1) / B, B, 0, stream>>>(dst, cnt, E);
    dis_kernel<<<(n + B - 1) / B, B, 0, stream>>>(cnt, dis, n);
    scan1_kernel<<<nb_scan, B, 0, stream>>>(cnt, rsp, bsum, n);
    scan2_kernel<<<1, B, 0, stream>>>(bsum, nb_scan);
    scan3_kernel<<<(n + B - 1) / B, B, 0, stream>>>(rsp, cursor, bsum, cnt, esrc, n);
    fill_kernel<<<(E + B - 1) / B, B, 0, stream>>>(src, dst, cursor, esrc, E);

    const int gemmGrid = (n + 63) / 64;
    const int gatherGrid = NCHUNK * ((n + 3) / 4);

    // layer 1
    gemm_128_128<false><<<gemmGrid, B, 0, stream>>>(x, W1, dis, bufA, n);
    zero_row_kernel<<<1, 128, 0, stream>>>(bufA, n);   // dummy row stays 0 for both layers
    gather_kernel<<<gatherGrid, B, 0, stream>>>(rsp, esrc, dis, bufA, b1, bufB, n);
    // layer 2
    gemm_128_128<true><<<gemmGrid, B, 0, stream>>>(bufB, W2, dis, bufA, n);
    gather_kernel<<<gatherGrid, B, 0, stream>>>(rsp, esrc, dis, bufA, b2, bufB, n);
    // head
    head_kernel<<<(n + 15) / 16, B, 0, stream>>>(bufB, Wh, bh, out, n);
}

// Round 7
// 400.105 us; speedup vs baseline: 1.3106x; 1.2224x over previous
//
#include <hip/hip_runtime.h>

#define CH 128
#define NCLS 16
#define CHK 16          // channels per chunk
#define NCHUNK 8        // 8 chunks of 16 == 128 channels, one per XCD
#define SCAN_IPB 1024   // items per block in scan pass 1

// ---------------------------------------------------------------- small utils
__global__ void zero_int_kernel(int* __restrict__ p, int n) {
    int i = blockIdx.x * blockDim.x + threadIdx.x;
    if (i < n) p[i] = 0;
}

__global__ void count_kernel(const int* __restrict__ dst,
                             int* __restrict__ cnt, int E) {
    int e = blockIdx.x * blockDim.x + threadIdx.x;
    if (e < E) atomicAdd(&cnt[dst[e]], 1);
}

__global__ void dis_kernel(const int* __restrict__ cnt,
                           float* __restrict__ dis, int n) {
    int i = blockIdx.x * blockDim.x + threadIdx.x;
    if (i < n) dis[i] = rsqrtf((float)cnt[i] + 1.0f);   // +1 = self-loop
}

// ---------------------------------------------------------------- scan (CSR)
// scan over cnt[i]+1 (self-loop embedded as a real edge, no padding)
__global__ __launch_bounds__(256) void scan1_kernel(
    const int* __restrict__ cnt, int* __restrict__ rsp,
    int* __restrict__ bsum, int n) {
    __shared__ int lds[256];
    int t = threadIdx.x, b = blockIdx.x;
    int base = b * SCAN_IPB + t * 4;
    int v[4];
    int s = 0;
#pragma unroll
    for (int k = 0; k < 4; k++) {
        v[k] = (base + k < n) ? (cnt[base + k] + 1) : 0;
        s += v[k];
    }
    lds[t] = s;
    __syncthreads();
    for (int off = 1; off < 256; off <<= 1) {
        int x = (t >= off) ? lds[t - off] : 0;
        __syncthreads();
        lds[t] += x;
        __syncthreads();
    }
    int incl = lds[t];
    int run = incl - s;   // exclusive across threads
#pragma unroll
    for (int k = 0; k < 4; k++) {
        if (base + k < n) rsp[base + k] = run;
        run += v[k];
    }
    if (t == 255) bsum[b] = incl;
}

__global__ __launch_bounds__(256) void scan2_kernel(int* __restrict__ bsum, int nb) {
    __shared__ int lds[256];
    int t = threadIdx.x;
    int s = (t < nb) ? bsum[t] : 0;
    lds[t] = s;
    __syncthreads();
    for (int off = 1; off < 256; off <<= 1) {
        int x = (t >= off) ? lds[t - off] : 0;
        __syncthreads();
        lds[t] += x;
        __syncthreads();
    }
    if (t < nb) bsum[t] = lds[t] - s;   // exclusive
}

// finalize rsp, init cursor, write the self-edge at slot 0 of each row
__global__ void scan3_kernel(int* __restrict__ rsp, int* __restrict__ cursor,
                             const int* __restrict__ bsum,
                             const int* __restrict__ cnt,
                             int* __restrict__ esrc, int n) {
    int i = blockIdx.x * blockDim.x + threadIdx.x;
    if (i >= n) return;
    int v = rsp[i] + bsum[i >> 10];   // >>10 == /SCAN_IPB
    rsp[i] = v;
    cursor[i] = v + 1;                // slot v holds the self-edge
    esrc[v] = i;                      // self-loop as a real edge
    if (i == n - 1) rsp[n] = v + cnt[i] + 1;
}

__global__ void fill_kernel(const int* __restrict__ src, const int* __restrict__ dst,
                            int* __restrict__ cursor, int* __restrict__ esrc, int E) {
    int e = blockIdx.x * blockDim.x + threadIdx.x;
    if (e >= E) return;
    int p = atomicAdd(&cursor[dst[e]], 1);
    esrc[p] = src[e];
}

// ---------------------------------------------------------------- GEMM 128x128
// C is CHUNK-MAJOR: C[chunk][row][16], chunk = col/16, each row PRE-SCALED by
// dis[row] (gather never touches dis[src]).
template <bool RELU_IN>
__global__ __launch_bounds__(256) void gemm_128_128(
    const float* __restrict__ A, const float* __restrict__ W,
    const float* __restrict__ dis, float* __restrict__ C, int n_rows) {
    __shared__ float As[64][33];
    __shared__ float Ws[32][132];

    const int tid = threadIdx.x;
    const int bm0 = blockIdx.x * 64;
    const int tc = tid & 31;
    const int tr = tid >> 5;

    float acc[8][4];
#pragma unroll
    for (int i = 0; i < 8; i++)
#pragma unroll
        for (int j = 0; j < 4; j++) acc[i][j] = 0.0f;

    for (int k0 = 0; k0 < 128; k0 += 32) {
#pragma unroll
        for (int i = 0; i < 8; i++) {
            int l = tid + i * 256;
            int r = l >> 5, c = l & 31;
            int gr = bm0 + r;
            float v = (gr < n_rows) ? A[(size_t)gr * CH + k0 + c] : 0.0f;
            if (RELU_IN) v = fmaxf(v, 0.0f);
            As[r][c] = v;
        }
#pragma unroll
        for (int i = 0; i < 16; i++) {
            int l = tid + i * 256;
            int r = l >> 7, c = l & 127;
            Ws[r][c] = W[(k0 + r) * CH + c];
        }
        __syncthreads();
#pragma unroll
        for (int kk = 0; kk < 32; kk++) {
            float4 b = *(const float4*)&Ws[kk][tc * 4];
            float a[8];
#pragma unroll
            for (int i = 0; i < 8; i++) a[i] = As[tr * 8 + i][kk];
#pragma unroll
            for (int i = 0; i < 8; i++) {
                acc[i][0] = fmaf(a[i], b.x, acc[i][0]);
                acc[i][1] = fmaf(a[i], b.y, acc[i][1]);
                acc[i][2] = fmaf(a[i], b.z, acc[i][2]);
                acc[i][3] = fmaf(a[i], b.w, acc[i][3]);
            }
        }
        __syncthreads();
    }
    const int chunk = tc >> 2;          // 16-channel chunk
    const int chOff = (tc & 3) * 4;     // float offset inside chunk
    float* __restrict__ Cc = C + (size_t)chunk * n_rows * CHK + chOff;
#pragma unroll
    for (int i = 0; i < 8; i++) {
        int gr = bm0 + tr * 8 + i;
        if (gr < n_rows) {
            float d = dis[gr];
            float4 v = make_float4(acc[i][0] * d, acc[i][1] * d,
                                   acc[i][2] * d, acc[i][3] * d);
            *(float4*)&Cc[(size_t)gr * CHK] = v;
        }
    }
}

// ---------------------------------------------------------------- CSR gather
// wave = (8 nodes, 1 chunk); chunk = blockIdx%8 pins the 3.2MB slice per XCD.
// Lane = (g = lane>>3 node slot, c2 = lane&7 float2 of the 64B chunk row).
// Each 8-lane group walks its own node's edge list: esrc[j] is a broadcast
// load (same addr within group), the h row is one 64B line per group.
// NO cross-lane reduce: lane's accumulator IS the final (node, 2ch) sum.
//   out[i, c*16+:16] = bias + dis[i] * sum_edges hC[c][esrc]
__global__ __launch_bounds__(256) void gather_kernel(
    const int* __restrict__ rsp, const int* __restrict__ esrc,
    const float* __restrict__ dis, const float* __restrict__ hC,
    const float* __restrict__ bias, float* __restrict__ out, int n) {
    int c = blockIdx.x & 7;
    int wv = threadIdx.x >> 6;
    int lane = threadIdx.x & 63;
    int g = lane >> 3;    // node slot 0..7
    int c2 = lane & 7;    // float2 within the 16-channel row
    int i = (blockIdx.x >> 3) * 32 + wv * 8 + g;
    bool valid = (i < n);
    int iw = valid ? i : 0;
    const float2* __restrict__ h2 = (const float2*)(hC + (size_t)c * n * CHK);

    int beg = valid ? rsp[iw] : 0;
    int end = valid ? rsp[iw + 1] : 0;
    float ax = 0.f, ay = 0.f;
    int j = beg;
    for (; j + 4 <= end; j += 4) {       // 4 independent esrc->h chains
        int s0 = esrc[j + 0];
        int s1 = esrc[j + 1];
        int s2 = esrc[j + 2];
        int s3 = esrc[j + 3];
        float2 v0 = h2[(size_t)s0 * 8 + c2];
        float2 v1 = h2[(size_t)s1 * 8 + c2];
        float2 v2 = h2[(size_t)s2 * 8 + c2];
        float2 v3 = h2[(size_t)s3 * 8 + c2];
        ax += v0.x; ay += v0.y;
        ax += v1.x; ay += v1.y;
        ax += v2.x; ay += v2.y;
        ax += v3.x; ay += v3.y;
    }
    for (; j < end; j++) {
        int s0 = esrc[j];
        float2 v0 = h2[(size_t)s0 * 8 + c2];
        ax += v0.x; ay += v0.y;
    }
    if (valid) {
        float di = dis[iw];
        float2 bv = ((const float2*)bias)[c * 8 + c2];
        float2 o = make_float2(bv.x + di * ax, bv.y + di * ay);
        ((float2*)out)[(size_t)iw * 64 + c * 8 + c2] = o;
    }
}

// ---------------------------------------------------------------- head
__global__ __launch_bounds__(256) void head_kernel(
    const float* __restrict__ A, const float* __restrict__ Wh,
    const float* __restrict__ bh, float* __restrict__ out, int n) {
    __shared__ float Ws[CH * NCLS];
    __shared__ float As[16][129];
    const int tid = threadIdx.x;
    const int n0 = blockIdx.x * 16;
#pragma unroll
    for (int i = 0; i < 8; i++) {
        int l = tid + i * 256;
        Ws[l] = Wh[l];
    }
#pragma unroll
    for (int i = 0; i < 8; i++) {
        int l = tid + i * 256;
        int r = l >> 7, c = l & 127;
        int gr = n0 + r;
        As[r][c] = (gr < n) ? fmaxf(A[(size_t)gr * CH + c], 0.0f) : 0.0f;
    }
    __syncthreads();
    int r = tid >> 4, c = tid & 15;
    float acc = bh[c];
#pragma unroll
    for (int k = 0; k < CH; k++) acc = fmaf(As[r][k], Ws[k * NCLS + c], acc);
    int gr = n0 + r;
    if (gr < n) out[(size_t)gr * NCLS + c] = acc;
}

// ---------------------------------------------------------------- launch
extern "C" void kernel_launch(void* const* d_in, const int* in_sizes, int n_in,
                              void* d_out, int out_size, void* d_ws, size_t ws_size,
                              hipStream_t stream) {
    const float* x  = (const float*)d_in[0];
    const int*   ei = (const int*)d_in[1];
    const float* W1 = (const float*)d_in[2];
    const float* b1 = (const float*)d_in[3];
    const float* W2 = (const float*)d_in[4];
    const float* b2 = (const float*)d_in[5];
    const float* Wh = (const float*)d_in[6];
    const float* bh = (const float*)d_in[7];
    float* out = (float*)d_out;

    const int n = in_sizes[0] / CH;   // 50000
    const int E = in_sizes[1] / 2;    // 800000
    const int* src = ei;
    const int* dst = ei + E;

    // workspace layout
    float* dis  = (float*)d_ws;                      // n
    float* bufA = dis + n;                           // n*128  chunk-major h'
    float* bufB = bufA + (size_t)n * CH;             // n*128  row-major
    int* cnt    = (int*)(bufB + (size_t)n * CH);     // n
    int* rsp    = cnt + n;                           // n+1 (CSR row starts)
    int* cursor = rsp + n + 1;                       // n
    int* bsum   = cursor + n;                        // up to 256
    int* esrc   = bsum + 256;                        // E + n (self-loops)

    const int B = 256;
    const int nb_scan = (n + SCAN_IPB - 1) / SCAN_IPB;   // 49

    // ---- CSR build (self-loops embedded) + normalization
    zero_int_kernel<<<(n + B - 1) / B, B, 0, stream>>>(cnt, n);
    count_kernel<<<(E + B - 1) / B, B, 0, stream>>>(dst, cnt, E);
    dis_kernel<<<(n + B - 1) / B, B, 0, stream>>>(cnt, dis, n);
    scan1_kernel<<<nb_scan, B, 0, stream>>>(cnt, rsp, bsum, n);
    scan2_kernel<<<1, B, 0, stream>>>(bsum, nb_scan);
    scan3_kernel<<<(n + B - 1) / B, B, 0, stream>>>(rsp, cursor, bsum, cnt, esrc, n);
    fill_kernel<<<(E + B - 1) / B, B, 0, stream>>>(src, dst, cursor, esrc, E);

    const int gemmGrid = (n + 63) / 64;
    const int gatherGrid = NCHUNK * ((n + 31) / 32);   // 32 nodes per block per chunk

    // layer 1
    gemm_128_128<false><<<gemmGrid, B, 0, stream>>>(x, W1, dis, bufA, n);
    gather_kernel<<<gatherGrid, B, 0, stream>>>(rsp, esrc, dis, bufA, b1, bufB, n);
    // layer 2
    gemm_128_128<true><<<gemmGrid, B, 0, stream>>>(bufB, W2, dis, bufA, n);
    gather_kernel<<<gatherGrid, B, 0, stream>>>(rsp, esrc, dis, bufA, b2, bufB, n);
    // head
    head_kernel<<<(n + 15) / 16, B, 0, stream>>>(bufB, Wh, bh, out, n);
}

// Round 8
// 387.466 us; speedup vs baseline: 1.3533x; 1.0326x over previous
//
#include <hip/hip_runtime.h>

#define CH 128
#define NCLS 16
#define CHK 16          // channels per chunk
#define NCHUNK 8        // 8 chunks of 16 == 128 channels, one per XCD
#define SCAN_IPB 1024   // items per block in scan pass 1
#define APITCH 136      // LDS row pitch (ushorts): 272B, 16B-aligned rows

typedef __attribute__((ext_vector_type(8))) short bf16x8;
typedef __attribute__((ext_vector_type(4))) float f32x4;

__device__ inline ushort f2bf(float f) {        // RTNE fp32 -> bf16 bits
    unsigned u = __float_as_uint(f);
    unsigned r = u + 0x7fffu + ((u >> 16) & 1u);
    return (ushort)(r >> 16);
}
__device__ inline float bf2f(ushort b) {
    return __uint_as_float(((unsigned)b) << 16);
}

// ---------------------------------------------------------------- small utils
__global__ void zero_int_kernel(int* __restrict__ p, int n) {
    int i = blockIdx.x * blockDim.x + threadIdx.x;
    if (i < n) p[i] = 0;
}

__global__ void count_kernel(const int* __restrict__ dst,
                             int* __restrict__ cnt, int E) {
    int e = blockIdx.x * blockDim.x + threadIdx.x;
    if (e < E) atomicAdd(&cnt[dst[e]], 1);
}

__global__ void dis_kernel(const int* __restrict__ cnt,
                           float* __restrict__ dis, int n) {
    int i = blockIdx.x * blockDim.x + threadIdx.x;
    if (i < n) dis[i] = rsqrtf((float)cnt[i] + 1.0f);   // +1 = self-loop
}

// convert + transpose one 128x128 W: Wt[n][k] = W[k][n], split hi/lo bf16
__global__ void convw_kernel(const float* __restrict__ W,
                             ushort* __restrict__ Whi, ushort* __restrict__ Wlo) {
    int t = blockIdx.x * blockDim.x + threadIdx.x;
    if (t >= CH * CH) return;
    int k = t >> 7, nn = t & 127;
    float v = W[t];
    ushort h = f2bf(v);
    ushort l = f2bf(v - bf2f(h));
    Whi[nn * CH + k] = h;
    Wlo[nn * CH + k] = l;
}

// ---------------------------------------------------------------- scan (CSR)
__global__ __launch_bounds__(256) void scan1_kernel(
    const int* __restrict__ cnt, int* __restrict__ rsp,
    int* __restrict__ bsum, int n) {
    __shared__ int lds[256];
    int t = threadIdx.x, b = blockIdx.x;
    int base = b * SCAN_IPB + t * 4;
    int v[4];
    int s = 0;
#pragma unroll
    for (int k = 0; k < 4; k++) {
        v[k] = (base + k < n) ? (cnt[base + k] + 1) : 0;
        s += v[k];
    }
    lds[t] = s;
    __syncthreads();
    for (int off = 1; off < 256; off <<= 1) {
        int x = (t >= off) ? lds[t - off] : 0;
        __syncthreads();
        lds[t] += x;
        __syncthreads();
    }
    int incl = lds[t];
    int run = incl - s;   // exclusive across threads
#pragma unroll
    for (int k = 0; k < 4; k++) {
        if (base + k < n) rsp[base + k] = run;
        run += v[k];
    }
    if (t == 255) bsum[b] = incl;
}

__global__ __launch_bounds__(256) void scan2_kernel(int* __restrict__ bsum, int nb) {
    __shared__ int lds[256];
    int t = threadIdx.x;
    int s = (t < nb) ? bsum[t] : 0;
    lds[t] = s;
    __syncthreads();
    for (int off = 1; off < 256; off <<= 1) {
        int x = (t >= off) ? lds[t - off] : 0;
        __syncthreads();
        lds[t] += x;
        __syncthreads();
    }
    if (t < nb) bsum[t] = lds[t] - s;   // exclusive
}

__global__ void scan3_kernel(int* __restrict__ rsp, int* __restrict__ cursor,
                             const int* __restrict__ bsum,
                             const int* __restrict__ cnt,
                             int* __restrict__ esrc, int n) {
    int i = blockIdx.x * blockDim.x + threadIdx.x;
    if (i >= n) return;
    int v = rsp[i] + bsum[i >> 10];   // >>10 == /SCAN_IPB
    rsp[i] = v;
    cursor[i] = v + 1;                // slot v holds the self-edge
    esrc[v] = i;                      // self-loop as a real edge
    if (i == n - 1) rsp[n] = v + cnt[i] + 1;
}

__global__ void fill_kernel(const int* __restrict__ src, const int* __restrict__ dst,
                            int* __restrict__ cursor, int* __restrict__ esrc, int E) {
    int e = blockIdx.x * blockDim.x + threadIdx.x;
    if (e >= E) return;
    int p = atomicAdd(&cursor[dst[e]], 1);
    esrc[p] = src[e];
}

// ---------------------------------------------------------------- MFMA GEMM
// C[n_rows x 128] = relu?(A) @ W via bf16 hi/lo split (hi*hi + hi*lo + lo*hi).
// Bt* is W transposed [n][k] bf16 (B^T pattern, verified m92 layout).
// C written CHUNK-MAJOR C[chunk][row][16], rows PRE-SCALED by dis[row].
template <bool RELU_IN>
__global__ __launch_bounds__(256) void gemm_mfma(
    const float* __restrict__ A, const ushort* __restrict__ Bthi,
    const ushort* __restrict__ Btlo, const float* __restrict__ dis,
    float* __restrict__ C, int n_rows) {
    __shared__ ushort Ahi[64][APITCH];
    __shared__ ushort Alo[64][APITCH];
    const int tid = threadIdx.x;
    const int bm0 = blockIdx.x * 64;

    // ---- stage A tile: fp32 -> hi/lo bf16 in LDS (64 rows x 128 k)
    {
        int r = tid >> 2;
        int gr = bm0 + r;
        bool v = (gr < n_rows);
        const float* Arow = A + (size_t)gr * CH;
#pragma unroll
        for (int i = 0; i < 8; i++) {
            int c = (tid & 3) * 4 + i * 16;
            float4 f = v ? *(const float4*)&Arow[c] : make_float4(0.f, 0.f, 0.f, 0.f);
            if (RELU_IN) {
                f.x = fmaxf(f.x, 0.f); f.y = fmaxf(f.y, 0.f);
                f.z = fmaxf(f.z, 0.f); f.w = fmaxf(f.w, 0.f);
            }
            ushort4 h, l;
            h.x = f2bf(f.x); l.x = f2bf(f.x - bf2f(h.x));
            h.y = f2bf(f.y); l.y = f2bf(f.y - bf2f(h.y));
            h.z = f2bf(f.z); l.z = f2bf(f.z - bf2f(h.z));
            h.w = f2bf(f.w); l.w = f2bf(f.w - bf2f(h.w));
            *(ushort4*)&Ahi[r][c] = h;
            *(ushort4*)&Alo[r][c] = l;
        }
    }
    __syncthreads();

    // ---- MFMA: wave wv covers rows [wv*16, wv*16+16) x all 128 cols
    const int wv = tid >> 6;
    const int lane = tid & 63;
    const int col = lane & 15;     // A row-in-frag / B col / C col
    const int quad = lane >> 4;    // k-block for A/B; row-quad for C
    const int mrow = wv * 16 + col;

    f32x4 acc[8];
#pragma unroll
    for (int nt = 0; nt < 8; nt++) acc[nt] = (f32x4){0.f, 0.f, 0.f, 0.f};

#pragma unroll
    for (int k0 = 0; k0 < 4; k0++) {
        const int kb = k0 * 32 + quad * 8;
        bf16x8 ah = *(const bf16x8*)&Ahi[mrow][kb];
        bf16x8 al = *(const bf16x8*)&Alo[mrow][kb];
#pragma unroll
        for (int nt = 0; nt < 8; nt++) {
            const int boff = (nt * 16 + col) * CH + kb;
            bf16x8 bh = *(const bf16x8*)&Bthi[boff];
            bf16x8 bl = *(const bf16x8*)&Btlo[boff];
            acc[nt] = __builtin_amdgcn_mfma_f32_16x16x32_bf16(ah, bh, acc[nt], 0, 0, 0);
            acc[nt] = __builtin_amdgcn_mfma_f32_16x16x32_bf16(ah, bl, acc[nt], 0, 0, 0);
            acc[nt] = __builtin_amdgcn_mfma_f32_16x16x32_bf16(al, bh, acc[nt], 0, 0, 0);
        }
    }

    // ---- epilogue: C/D layout col=lane&15, row=quad*4+reg (m89-verified)
#pragma unroll
    for (int reg = 0; reg < 4; reg++) {
        int gr = bm0 + wv * 16 + quad * 4 + reg;
        if (gr < n_rows) {
            float d = dis[gr];
#pragma unroll
            for (int nt = 0; nt < 8; nt++) {
                C[((size_t)nt * n_rows + gr) * CHK + col] = acc[nt][reg] * d;
            }
        }
    }
}

// ---------------------------------------------------------------- CSR gather
// wave = (8 nodes, 1 chunk); chunk = blockIdx%8 pins the 3.2MB slice per XCD.
// Lane = (g = lane>>3 node slot, c2 = lane&7 float2 of the 64B chunk row).
__global__ __launch_bounds__(256) void gather_kernel(
    const int* __restrict__ rsp, const int* __restrict__ esrc,
    const float* __restrict__ dis, const float* __restrict__ hC,
    const float* __restrict__ bias, float* __restrict__ out, int n) {
    int c = blockIdx.x & 7;
    int wv = threadIdx.x >> 6;
    int lane = threadIdx.x & 63;
    int g = lane >> 3;    // node slot 0..7
    int c2 = lane & 7;    // float2 within the 16-channel row
    int i = (blockIdx.x >> 3) * 32 + wv * 8 + g;
    bool valid = (i < n);
    int iw = valid ? i : 0;
    const float2* __restrict__ h2 = (const float2*)(hC + (size_t)c * n * CHK);

    int beg = valid ? rsp[iw] : 0;
    int end = valid ? rsp[iw + 1] : 0;
    float ax = 0.f, ay = 0.f;
    int j = beg;
    for (; j + 4 <= end; j += 4) {       // 4 independent esrc->h chains
        int s0 = esrc[j + 0];
        int s1 = esrc[j + 1];
        int s2 = esrc[j + 2];
        int s3 = esrc[j + 3];
        float2 v0 = h2[(size_t)s0 * 8 + c2];
        float2 v1 = h2[(size_t)s1 * 8 + c2];
        float2 v2 = h2[(size_t)s2 * 8 + c2];
        float2 v3 = h2[(size_t)s3 * 8 + c2];
        ax += v0.x; ay += v0.y;
        ax += v1.x; ay += v1.y;
        ax += v2.x; ay += v2.y;
        ax += v3.x; ay += v3.y;
    }
    for (; j < end; j++) {
        int s0 = esrc[j];
        float2 v0 = h2[(size_t)s0 * 8 + c2];
        ax += v0.x; ay += v0.y;
    }
    if (valid) {
        float di = dis[iw];
        float2 bv = ((const float2*)bias)[c * 8 + c2];
        float2 o = make_float2(bv.x + di * ax, bv.y + di * ay);
        ((float2*)out)[(size_t)iw * 64 + c * 8 + c2] = o;
    }
}

// ---------------------------------------------------------------- head
__global__ __launch_bounds__(256) void head_kernel(
    const float* __restrict__ A, const float* __restrict__ Wh,
    const float* __restrict__ bh, float* __restrict__ out, int n) {
    __shared__ float Ws[CH * NCLS];
    __shared__ float As[16][129];
    const int tid = threadIdx.x;
    const int n0 = blockIdx.x * 16;
#pragma unroll
    for (int i = 0; i < 8; i++) {
        int l = tid + i * 256;
        Ws[l] = Wh[l];
    }
#pragma unroll
    for (int i = 0; i < 8; i++) {
        int l = tid + i * 256;
        int r = l >> 7, c = l & 127;
        int gr = n0 + r;
        As[r][c] = (gr < n) ? fmaxf(A[(size_t)gr * CH + c], 0.0f) : 0.0f;
    }
    __syncthreads();
    int r = tid >> 4, c = tid & 15;
    float acc = bh[c];
#pragma unroll
    for (int k = 0; k < CH; k++) acc = fmaf(As[r][k], Ws[k * NCLS + c], acc);
    int gr = n0 + r;
    if (gr < n) out[(size_t)gr * NCLS + c] = acc;
}

// ---------------------------------------------------------------- launch
extern "C" void kernel_launch(void* const* d_in, const int* in_sizes, int n_in,
                              void* d_out, int out_size, void* d_ws, size_t ws_size,
                              hipStream_t stream) {
    const float* x  = (const float*)d_in[0];
    const int*   ei = (const int*)d_in[1];
    const float* W1 = (const float*)d_in[2];
    const float* b1 = (const float*)d_in[3];
    const float* W2 = (const float*)d_in[4];
    const float* b2 = (const float*)d_in[5];
    const float* Wh = (const float*)d_in[6];
    const float* bh = (const float*)d_in[7];
    float* out = (float*)d_out;

    const int n = in_sizes[0] / CH;   // 50000
    const int E = in_sizes[1] / 2;    // 800000
    const int* src = ei;
    const int* dst = ei + E;

    // workspace layout (Wt first: 4 x 16384 ushorts = 128 KB, keeps 16B align)
    ushort* w1hi = (ushort*)d_ws;                    // 16384
    ushort* w1lo = w1hi + CH * CH;
    ushort* w2hi = w1lo + CH * CH;
    ushort* w2lo = w2hi + CH * CH;
    float* dis  = (float*)(w2lo + CH * CH);          // n
    float* bufA = dis + n;                           // n*128  chunk-major h'
    float* bufB = bufA + (size_t)n * CH;             // n*128  row-major
    int* cnt    = (int*)(bufB + (size_t)n * CH);     // n
    int* rsp    = cnt + n;                           // n+1 (CSR row starts)
    int* cursor = rsp + n + 1;                       // n
    int* bsum   = cursor + n;                        // up to 256
    int* esrc   = bsum + 256;                        // E + n (self-loops)

    const int B = 256;
    const int nb_scan = (n + SCAN_IPB - 1) / SCAN_IPB;   // 49

    // ---- CSR build (self-loops embedded) + normalization + W conversion
    zero_int_kernel<<<(n + B - 1) / B, B, 0, stream>>>(cnt, n);
    count_kernel<<<(E + B - 1) / B, B, 0, stream>>>(dst, cnt, E);
    dis_kernel<<<(n + B - 1) / B, B, 0, stream>>>(cnt, dis, n);
    scan1_kernel<<<nb_scan, B, 0, stream>>>(cnt, rsp, bsum, n);
    scan2_kernel<<<1, B, 0, stream>>>(bsum, nb_scan);
    scan3_kernel<<<(n + B - 1) / B, B, 0, stream>>>(rsp, cursor, bsum, cnt, esrc, n);
    fill_kernel<<<(E + B - 1) / B, B, 0, stream>>>(src, dst, cursor, esrc, E);
    convw_kernel<<<(CH * CH + B - 1) / B, B, 0, stream>>>(W1, w1hi, w1lo);
    convw_kernel<<<(CH * CH + B - 1) / B, B, 0, stream>>>(W2, w2hi, w2lo);

    const int gemmGrid = (n + 63) / 64;
    const int gatherGrid = NCHUNK * ((n + 31) / 32);   // 32 nodes per block per chunk

    // layer 1
    gemm_mfma<false><<<gemmGrid, B, 0, stream>>>(x, w1hi, w1lo, dis, bufA, n);
    gather_kernel<<<gatherGrid, B, 0, stream>>>(rsp, esrc, dis, bufA, b1, bufB, n);
    // layer 2
    gemm_mfma<true><<<gemmGrid, B, 0, stream>>>(bufB, w2hi, w2lo, dis, bufA, n);
    gather_kernel<<<gatherGrid, B, 0, stream>>>(rsp, esrc, dis, bufA, b2, bufB, n);
    // head
    head_kernel<<<(n + 15) / 16, B, 0, stream>>>(bufB, Wh, bh, out, n);
}

// Round 9
// 381.234 us; speedup vs baseline: 1.3754x; 1.0163x over previous
//
#include <hip/hip_runtime.h>

#define CH 128
#define NCLS 16
#define CHK 16          // channels per chunk
#define NCHUNK 8        // 8 chunks of 16 == 128 channels, one per XCD
#define SCAN_IPB 1024   // items per block in scan pass 1

typedef __attribute__((ext_vector_type(8))) short bf16x8;
typedef __attribute__((ext_vector_type(4))) float f32x4;

__device__ inline ushort f2bf(float f) {        // RTNE fp32 -> bf16 bits
    unsigned u = __float_as_uint(f);
    unsigned r = u + 0x7fffu + ((u >> 16) & 1u);
    return (ushort)(r >> 16);
}
__device__ inline float bf2f(ushort b) {
    return __uint_as_float(((unsigned)b) << 16);
}

// ---------------------------------------------------------------- small utils
__global__ void zero_int_kernel(int* __restrict__ p, int n) {
    int i = blockIdx.x * blockDim.x + threadIdx.x;
    if (i < n) p[i] = 0;
}

__global__ void count_kernel(const int* __restrict__ dst,
                             int* __restrict__ cnt, int E) {
    int e = blockIdx.x * blockDim.x + threadIdx.x;
    if (e < E) atomicAdd(&cnt[dst[e]], 1);
}

__global__ void dis_kernel(const int* __restrict__ cnt,
                           float* __restrict__ dis, int n) {
    int i = blockIdx.x * blockDim.x + threadIdx.x;
    if (i < n) dis[i] = rsqrtf((float)cnt[i] + 1.0f);   // +1 = self-loop
}

// convert + transpose one 128x128 W: Wt[n][k] = W[k][n], split hi/lo bf16
__global__ void convw_kernel(const float* __restrict__ W,
                             ushort* __restrict__ Whi, ushort* __restrict__ Wlo) {
    int t = blockIdx.x * blockDim.x + threadIdx.x;
    if (t >= CH * CH) return;
    int k = t >> 7, nn = t & 127;
    float v = W[t];
    ushort h = f2bf(v);
    ushort l = f2bf(v - bf2f(h));
    Whi[nn * CH + k] = h;
    Wlo[nn * CH + k] = l;
}

// ---------------------------------------------------------------- scan (CSR)
__global__ __launch_bounds__(256) void scan1_kernel(
    const int* __restrict__ cnt, int* __restrict__ rsp,
    int* __restrict__ bsum, int n) {
    __shared__ int lds[256];
    int t = threadIdx.x, b = blockIdx.x;
    int base = b * SCAN_IPB + t * 4;
    int v[4];
    int s = 0;
#pragma unroll
    for (int k = 0; k < 4; k++) {
        v[k] = (base + k < n) ? (cnt[base + k] + 1) : 0;
        s += v[k];
    }
    lds[t] = s;
    __syncthreads();
    for (int off = 1; off < 256; off <<= 1) {
        int x = (t >= off) ? lds[t - off] : 0;
        __syncthreads();
        lds[t] += x;
        __syncthreads();
    }
    int incl = lds[t];
    int run = incl - s;   // exclusive across threads
#pragma unroll
    for (int k = 0; k < 4; k++) {
        if (base + k < n) rsp[base + k] = run;
        run += v[k];
    }
    if (t == 255) bsum[b] = incl;
}

__global__ __launch_bounds__(256) void scan2_kernel(int* __restrict__ bsum, int nb) {
    __shared__ int lds[256];
    int t = threadIdx.x;
    int s = (t < nb) ? bsum[t] : 0;
    lds[t] = s;
    __syncthreads();
    for (int off = 1; off < 256; off <<= 1) {
        int x = (t >= off) ? lds[t - off] : 0;
        __syncthreads();
        lds[t] += x;
        __syncthreads();
    }
    if (t < nb) bsum[t] = lds[t] - s;   // exclusive
}

__global__ void scan3_kernel(int* __restrict__ rsp, int* __restrict__ cursor,
                             const int* __restrict__ bsum,
                             const int* __restrict__ cnt,
                             int* __restrict__ esrc, int n) {
    int i = blockIdx.x * blockDim.x + threadIdx.x;
    if (i >= n) return;
    int v = rsp[i] + bsum[i >> 10];   // >>10 == /SCAN_IPB
    rsp[i] = v;
    cursor[i] = v + 1;                // slot v holds the self-edge
    esrc[v] = i;                      // self-loop as a real edge
    if (i == n - 1) rsp[n] = v + cnt[i] + 1;
}

__global__ void fill_kernel(const int* __restrict__ src, const int* __restrict__ dst,
                            int* __restrict__ cursor, int* __restrict__ esrc, int E) {
    int e = blockIdx.x * blockDim.x + threadIdx.x;
    if (e >= E) return;
    int p = atomicAdd(&cursor[dst[e]], 1);
    esrc[p] = src[e];
}

// ---------------------------------------------------------------- MFMA GEMM v2
// C[n_rows x 128] = relu?(A) @ W via bf16 hi/lo split (hi*hi + hi*lo + lo*hi).
// NO LDS, NO barrier: rows are wave-partitioned so A has zero cross-wave
// reuse -- each lane builds its A-frags from 2 predicated float4 loads.
// B (Wt hi/lo, 64KB) streams from global (L2-hot). grid.y=2 splits N-tiles.
// C written CHUNK-MAJOR C[chunk][row][16], rows PRE-SCALED by dis[row].
template <bool RELU_IN>
__global__ __launch_bounds__(256, 4) void gemm_mfma(
    const float* __restrict__ A, const ushort* __restrict__ Bthi,
    const ushort* __restrict__ Btlo, const float* __restrict__ dis,
    float* __restrict__ C, int n_rows) {
    const int tid = threadIdx.x;
    const int bm0 = blockIdx.x * 64;
    const int wv = tid >> 6;
    const int lane = tid & 63;
    const int col = lane & 15;     // A row-in-frag / B col / C col
    const int quad = lane >> 4;    // k-block for A/B; row-quad for C
    const int arow = bm0 + wv * 16 + col;    // this lane's A row
    const bool av = (arow < n_rows);
    const float* __restrict__ Arow = A + (size_t)arow * CH;

    // ---- A fragments: 4 k0-steps, hi/lo, straight from global
    bf16x8 ah[4], al[4];
#pragma unroll
    for (int k0 = 0; k0 < 4; k0++) {
        const int kb = k0 * 32 + quad * 8;
        float4 f0 = av ? *(const float4*)&Arow[kb]     : make_float4(0.f, 0.f, 0.f, 0.f);
        float4 f1 = av ? *(const float4*)&Arow[kb + 4] : make_float4(0.f, 0.f, 0.f, 0.f);
        if (RELU_IN) {
            f0.x = fmaxf(f0.x, 0.f); f0.y = fmaxf(f0.y, 0.f);
            f0.z = fmaxf(f0.z, 0.f); f0.w = fmaxf(f0.w, 0.f);
            f1.x = fmaxf(f1.x, 0.f); f1.y = fmaxf(f1.y, 0.f);
            f1.z = fmaxf(f1.z, 0.f); f1.w = fmaxf(f1.w, 0.f);
        }
        float fa[8] = {f0.x, f0.y, f0.z, f0.w, f1.x, f1.y, f1.z, f1.w};
#pragma unroll
        for (int j = 0; j < 8; j++) {
            ushort h = f2bf(fa[j]);
            ah[k0][j] = (short)h;
            al[k0][j] = (short)f2bf(fa[j] - bf2f(h));
        }
    }

    // ---- MFMA over 4 N-tiles (this grid.y half)
    const int ntBase = blockIdx.y * 4;
    f32x4 acc[4];
#pragma unroll
    for (int t = 0; t < 4; t++) acc[t] = (f32x4){0.f, 0.f, 0.f, 0.f};

#pragma unroll
    for (int t = 0; t < 4; t++) {
        const int nt = ntBase + t;
#pragma unroll
        for (int k0 = 0; k0 < 4; k0++) {
            const int kb = k0 * 32 + quad * 8;
            const int boff = (nt * 16 + col) * CH + kb;
            bf16x8 bh = *(const bf16x8*)&Bthi[boff];
            bf16x8 bl = *(const bf16x8*)&Btlo[boff];
            acc[t] = __builtin_amdgcn_mfma_f32_16x16x32_bf16(ah[k0], bh, acc[t], 0, 0, 0);
            acc[t] = __builtin_amdgcn_mfma_f32_16x16x32_bf16(ah[k0], bl, acc[t], 0, 0, 0);
            acc[t] = __builtin_amdgcn_mfma_f32_16x16x32_bf16(al[k0], bh, acc[t], 0, 0, 0);
        }
    }

    // ---- epilogue: C/D layout col=lane&15, row=quad*4+reg (m89-verified)
#pragma unroll
    for (int reg = 0; reg < 4; reg++) {
        int gr = bm0 + wv * 16 + quad * 4 + reg;
        if (gr < n_rows) {
            float d = dis[gr];
#pragma unroll
            for (int t = 0; t < 4; t++) {
                int nt = ntBase + t;
                C[((size_t)nt * n_rows + gr) * CHK + col] = acc[t][reg] * d;
            }
        }
    }
}

// ---------------------------------------------------------------- CSR gather
// wave = (16 nodes, 1 chunk); chunk = blockIdx%8 pins the 3.2MB slice/XCD.
// Lane = (g = lane>>2 node slot 0..15, q = lane&3 float4 of the 64B row):
// one dwordx4 wave-load covers 16 full chunk rows (16 lines, 16B/lane) --
// half the vmem instructions of the float2 variant (TA-throughput bound).
// NO cross-lane reduce: lane's float4 acc IS the final (node, 4ch) sum.
__global__ __launch_bounds__(256) void gather_kernel(
    const int* __restrict__ rsp, const int* __restrict__ esrc,
    const float* __restrict__ dis, const float* __restrict__ hC,
    const float* __restrict__ bias, float* __restrict__ out, int n) {
    int c = blockIdx.x & 7;
    int wv = threadIdx.x >> 6;
    int lane = threadIdx.x & 63;
    int g = lane >> 2;    // node slot 0..15
    int q = lane & 3;     // float4 within the 16-channel row
    int i = (blockIdx.x >> 3) * 64 + wv * 16 + g;
    bool valid = (i < n);
    int iw = valid ? i : 0;
    const float4* __restrict__ h4 = (const float4*)(hC + (size_t)c * n * CHK);

    int beg = valid ? rsp[iw] : 0;
    int end = valid ? rsp[iw + 1] : 0;
    float4 acc = make_float4(0.f, 0.f, 0.f, 0.f);
    int j = beg;
    for (; j + 4 <= end; j += 4) {       // 4 independent esrc->h chains
        int s0 = esrc[j + 0];
        int s1 = esrc[j + 1];
        int s2 = esrc[j + 2];
        int s3 = esrc[j + 3];
        float4 v0 = h4[(size_t)s0 * 4 + q];
        float4 v1 = h4[(size_t)s1 * 4 + q];
        float4 v2 = h4[(size_t)s2 * 4 + q];
        float4 v3 = h4[(size_t)s3 * 4 + q];
        acc.x += v0.x; acc.y += v0.y; acc.z += v0.z; acc.w += v0.w;
        acc.x += v1.x; acc.y += v1.y; acc.z += v1.z; acc.w += v1.w;
        acc.x += v2.x; acc.y += v2.y; acc.z += v2.z; acc.w += v2.w;
        acc.x += v3.x; acc.y += v3.y; acc.z += v3.z; acc.w += v3.w;
    }
    for (; j < end; j++) {
        int s0 = esrc[j];
        float4 v0 = h4[(size_t)s0 * 4 + q];
        acc.x += v0.x; acc.y += v0.y; acc.z += v0.z; acc.w += v0.w;
    }
    if (valid) {
        float di = dis[iw];
        float4 bv = ((const float4*)bias)[c * 4 + q];
        float4 o;
        o.x = bv.x + di * acc.x;
        o.y = bv.y + di * acc.y;
        o.z = bv.z + di * acc.z;
        o.w = bv.w + di * acc.w;
        ((float4*)out)[(size_t)iw * 32 + c * 4 + q] = o;
    }
}

// ---------------------------------------------------------------- head
__global__ __launch_bounds__(256) void head_kernel(
    const float* __restrict__ A, const float* __restrict__ Wh,
    const float* __restrict__ bh, float* __restrict__ out, int n) {
    __shared__ float Ws[CH * NCLS];
    __shared__ float As[16][129];
    const int tid = threadIdx.x;
    const int n0 = blockIdx.x * 16;
#pragma unroll
    for (int i = 0; i < 8; i++) {
        int l = tid + i * 256;
        Ws[l] = Wh[l];
    }
#pragma unroll
    for (int i = 0; i < 8; i++) {
        int l = tid + i * 256;
        int r = l >> 7, c = l & 127;
        int gr = n0 + r;
        As[r][c] = (gr < n) ? fmaxf(A[(size_t)gr * CH + c], 0.0f) : 0.0f;
    }
    __syncthreads();
    int r = tid >> 4, c = tid & 15;
    float acc = bh[c];
#pragma unroll
    for (int k = 0; k < CH; k++) acc = fmaf(As[r][k], Ws[k * NCLS + c], acc);
    int gr = n0 + r;
    if (gr < n) out[(size_t)gr * NCLS + c] = acc;
}

// ---------------------------------------------------------------- launch
extern "C" void kernel_launch(void* const* d_in, const int* in_sizes, int n_in,
                              void* d_out, int out_size, void* d_ws, size_t ws_size,
                              hipStream_t stream) {
    const float* x  = (const float*)d_in[0];
    const int*   ei = (const int*)d_in[1];
    const float* W1 = (const float*)d_in[2];
    const float* b1 = (const float*)d_in[3];
    const float* W2 = (const float*)d_in[4];
    const float* b2 = (const float*)d_in[5];
    const float* Wh = (const float*)d_in[6];
    const float* bh = (const float*)d_in[7];
    float* out = (float*)d_out;

    const int n = in_sizes[0] / CH;   // 50000
    const int E = in_sizes[1] / 2;    // 800000
    const int* src = ei;
    const int* dst = ei + E;

    // workspace layout (Wt first: 4 x 16384 ushorts = 128 KB, keeps 16B align)
    ushort* w1hi = (ushort*)d_ws;                    // 16384
    ushort* w1lo = w1hi + CH * CH;
    ushort* w2hi = w1lo + CH * CH;
    ushort* w2lo = w2hi + CH * CH;
    float* dis  = (float*)(w2lo + CH * CH);          // n
    float* bufA = dis + n;                           // n*128  chunk-major h'
    float* bufB = bufA + (size_t)n * CH;             // n*128  row-major
    int* cnt    = (int*)(bufB + (size_t)n * CH);     // n
    int* rsp    = cnt + n;                           // n+1 (CSR row starts)
    int* cursor = rsp + n + 1;                       // n
    int* bsum   = cursor + n;                        // up to 256
    int* esrc   = bsum + 256;                        // E + n (self-loops)

    const int B = 256;
    const int nb_scan = (n + SCAN_IPB - 1) / SCAN_IPB;   // 49

    // ---- CSR build (self-loops embedded) + normalization + W conversion
    zero_int_kernel<<<(n + B - 1) / B, B, 0, stream>>>(cnt, n);
    count_kernel<<<(E + B - 1) / B, B, 0, stream>>>(dst, cnt, E);
    dis_kernel<<<(n + B - 1) / B, B, 0, stream>>>(cnt, dis, n);
    scan1_kernel<<<nb_scan, B, 0, stream>>>(cnt, rsp, bsum, n);
    scan2_kernel<<<1, B, 0, stream>>>(bsum, nb_scan);
    scan3_kernel<<<(n + B - 1) / B, B, 0, stream>>>(rsp, cursor, bsum, cnt, esrc, n);
    fill_kernel<<<(E + B - 1) / B, B, 0, stream>>>(src, dst, cursor, esrc, E);
    convw_kernel<<<(CH * CH + B - 1) / B, B, 0, stream>>>(W1, w1hi, w1lo);
    convw_kernel<<<(CH * CH + B - 1) / B, B, 0, stream>>>(W2, w2hi, w2lo);

    const dim3 gemmGrid((n + 63) / 64, 2);
    const int gatherGrid = NCHUNK * ((n + 63) / 64);   // 64 nodes/block/chunk

    // layer 1
    gemm_mfma<false><<<gemmGrid, B, 0, stream>>>(x, w1hi, w1lo, dis, bufA, n);
    gather_kernel<<<gatherGrid, B, 0, stream>>>(rsp, esrc, dis, bufA, b1, bufB, n);
    // layer 2
    gemm_mfma<true><<<gemmGrid, B, 0, stream>>>(bufB, w2hi, w2lo, dis, bufA, n);
    gather_kernel<<<gatherGrid, B, 0, stream>>>(rsp, esrc, dis, bufA, b2, bufB, n);
    // head
    head_kernel<<<(n + 15) / 16, B, 0, stream>>>(bufB, Wh, bh, out, n);
}

// Round 10
// 371.639 us; speedup vs baseline: 1.4110x; 1.0258x over previous
//
#include <hip/hip_runtime.h>

#define CH 128
#define NCLS 16
#define CHK 16          // channels per chunk
#define NCHUNK 8        // 8 chunks of 16 == 128 channels, one per XCD
#define SCAN_IPB 1024   // items per block in scan pass 1

typedef __attribute__((ext_vector_type(8))) short bf16x8;
typedef __attribute__((ext_vector_type(4))) float f32x4;

__device__ inline ushort f2bf(float f) {        // RTNE fp32 -> bf16 bits
    unsigned u = __float_as_uint(f);
    unsigned r = u + 0x7fffu + ((u >> 16) & 1u);
    return (ushort)(r >> 16);
}
__device__ inline float bf2f(ushort b) {
    return __uint_as_float(((unsigned)b) << 16);
}

// ---------------------------------------------------------------- small utils
__global__ void zero_int_kernel(int* __restrict__ p, int n) {
    int i = blockIdx.x * blockDim.x + threadIdx.x;
    if (i < n) p[i] = 0;
}

// XCD-partitioned degree count: partition p = blockIdx&7 owns dst range
// [p*6250, ...); its cnt lines are touched by one XCD only -> local L2 RMW.
__global__ void count_kernel(const int* __restrict__ dst,
                             int* __restrict__ cnt, int E, int n) {
    int part = blockIdx.x & 7;
    int npp = (n + 7) >> 3;
    int lo = part * npp;
    int hi = min(n, lo + npp);
    int stride = (gridDim.x >> 3) * blockDim.x;
    for (int e = (blockIdx.x >> 3) * blockDim.x + threadIdx.x; e < E; e += stride) {
        int d = dst[e];
        if (d >= lo && d < hi) atomicAdd(&cnt[d], 1);
    }
}

__global__ void dis_kernel(const int* __restrict__ cnt,
                           float* __restrict__ dis, int n) {
    int i = blockIdx.x * blockDim.x + threadIdx.x;
    if (i < n) dis[i] = rsqrtf((float)cnt[i] + 1.0f);   // +1 = self-loop
}

// convert + transpose one 128x128 W: Wt[n][k] = W[k][n], split hi/lo bf16
__global__ void convw_kernel(const float* __restrict__ W,
                             ushort* __restrict__ Whi, ushort* __restrict__ Wlo) {
    int t = blockIdx.x * blockDim.x + threadIdx.x;
    if (t >= CH * CH) return;
    int k = t >> 7, nn = t & 127;
    float v = W[t];
    ushort h = f2bf(v);
    ushort l = f2bf(v - bf2f(h));
    Whi[nn * CH + k] = h;
    Wlo[nn * CH + k] = l;
}

// ---------------------------------------------------------------- scan (CSR)
__global__ __launch_bounds__(256) void scan1_kernel(
    const int* __restrict__ cnt, int* __restrict__ rsp,
    int* __restrict__ bsum, int n) {
    __shared__ int lds[256];
    int t = threadIdx.x, b = blockIdx.x;
    int base = b * SCAN_IPB + t * 4;
    int v[4];
    int s = 0;
#pragma unroll
    for (int k = 0; k < 4; k++) {
        v[k] = (base + k < n) ? (cnt[base + k] + 1) : 0;
        s += v[k];
    }
    lds[t] = s;
    __syncthreads();
    for (int off = 1; off < 256; off <<= 1) {
        int x = (t >= off) ? lds[t - off] : 0;
        __syncthreads();
        lds[t] += x;
        __syncthreads();
    }
    int incl = lds[t];
    int run = incl - s;   // exclusive across threads
#pragma unroll
    for (int k = 0; k < 4; k++) {
        if (base + k < n) rsp[base + k] = run;
        run += v[k];
    }
    if (t == 255) bsum[b] = incl;
}

__global__ __launch_bounds__(256) void scan2_kernel(int* __restrict__ bsum, int nb) {
    __shared__ int lds[256];
    int t = threadIdx.x;
    int s = (t < nb) ? bsum[t] : 0;
    lds[t] = s;
    __syncthreads();
    for (int off = 1; off < 256; off <<= 1) {
        int x = (t >= off) ? lds[t - off] : 0;
        __syncthreads();
        lds[t] += x;
        __syncthreads();
    }
    if (t < nb) bsum[t] = lds[t] - s;   // exclusive
}

__global__ void scan3_kernel(int* __restrict__ rsp, int* __restrict__ cursor,
                             const int* __restrict__ bsum,
                             const int* __restrict__ cnt,
                             int* __restrict__ esrc, int n) {
    int i = blockIdx.x * blockDim.x + threadIdx.x;
    if (i >= n) return;
    int v = rsp[i] + bsum[i >> 10];   // >>10 == /SCAN_IPB
    rsp[i] = v;
    cursor[i] = v + 1;                // slot v holds the self-edge
    esrc[v] = i;                      // self-loop as a real edge
    if (i == n - 1) rsp[n] = v + cnt[i] + 1;
}

// XCD-partitioned CSR fill: partition p = blockIdx&7 owns dst range
// [p*6250, ...). Its cursor range AND its contiguous esrc slice are touched
// by one XCD only -> atomics are local-L2 RMW, esrc lines written back once
// (kills the 16x write amplification seen in round 9: 53MB -> ~3.5MB).
__global__ void fill_kernel(const int* __restrict__ src, const int* __restrict__ dst,
                            int* __restrict__ cursor, int* __restrict__ esrc,
                            int E, int n) {
    int part = blockIdx.x & 7;
    int npp = (n + 7) >> 3;
    int lo = part * npp;
    int hi = min(n, lo + npp);
    int stride = (gridDim.x >> 3) * blockDim.x;
    for (int e = (blockIdx.x >> 3) * blockDim.x + threadIdx.x; e < E; e += stride) {
        int d = dst[e];
        if (d >= lo && d < hi) {
            int p = atomicAdd(&cursor[d], 1);
            esrc[p] = src[e];
        }
    }
}

// ---------------------------------------------------------------- MFMA GEMM v2
// C[n_rows x 128] = relu?(A) @ W via bf16 hi/lo split (hi*hi + hi*lo + lo*hi).
// NO LDS, NO barrier: rows are wave-partitioned so A has zero cross-wave
// reuse -- each lane builds its A-frags from 2 predicated float4 loads.
// B (Wt hi/lo, 64KB) streams from global (L2-hot). grid.y=2 splits N-tiles.
// C written CHUNK-MAJOR C[chunk][row][16], rows PRE-SCALED by dis[row].
template <bool RELU_IN>
__global__ __launch_bounds__(256, 4) void gemm_mfma(
    const float* __restrict__ A, const ushort* __restrict__ Bthi,
    const ushort* __restrict__ Btlo, const float* __restrict__ dis,
    float* __restrict__ C, int n_rows) {
    const int tid = threadIdx.x;
    const int bm0 = blockIdx.x * 64;
    const int wv = tid >> 6;
    const int lane = tid & 63;
    const int col = lane & 15;     // A row-in-frag / B col / C col
    const int quad = lane >> 4;    // k-block for A/B; row-quad for C
    const int arow = bm0 + wv * 16 + col;    // this lane's A row
    const bool av = (arow < n_rows);
    const float* __restrict__ Arow = A + (size_t)arow * CH;

    // ---- A fragments: 4 k0-steps, hi/lo, straight from global
    bf16x8 ah[4], al[4];
#pragma unroll
    for (int k0 = 0; k0 < 4; k0++) {
        const int kb = k0 * 32 + quad * 8;
        float4 f0 = av ? *(const float4*)&Arow[kb]     : make_float4(0.f, 0.f, 0.f, 0.f);
        float4 f1 = av ? *(const float4*)&Arow[kb + 4] : make_float4(0.f, 0.f, 0.f, 0.f);
        if (RELU_IN) {
            f0.x = fmaxf(f0.x, 0.f); f0.y = fmaxf(f0.y, 0.f);
            f0.z = fmaxf(f0.z, 0.f); f0.w = fmaxf(f0.w, 0.f);
            f1.x = fmaxf(f1.x, 0.f); f1.y = fmaxf(f1.y, 0.f);
            f1.z = fmaxf(f1.z, 0.f); f1.w = fmaxf(f1.w, 0.f);
        }
        float fa[8] = {f0.x, f0.y, f0.z, f0.w, f1.x, f1.y, f1.z, f1.w};
#pragma unroll
        for (int j = 0; j < 8; j++) {
            ushort h = f2bf(fa[j]);
            ah[k0][j] = (short)h;
            al[k0][j] = (short)f2bf(fa[j] - bf2f(h));
        }
    }

    // ---- MFMA over 4 N-tiles (this grid.y half)
    const int ntBase = blockIdx.y * 4;
    f32x4 acc[4];
#pragma unroll
    for (int t = 0; t < 4; t++) acc[t] = (f32x4){0.f, 0.f, 0.f, 0.f};

#pragma unroll
    for (int t = 0; t < 4; t++) {
        const int nt = ntBase + t;
#pragma unroll
        for (int k0 = 0; k0 < 4; k0++) {
            const int kb = k0 * 32 + quad * 8;
            const int boff = (nt * 16 + col) * CH + kb;
            bf16x8 bh = *(const bf16x8*)&Bthi[boff];
            bf16x8 bl = *(const bf16x8*)&Btlo[boff];
            acc[t] = __builtin_amdgcn_mfma_f32_16x16x32_bf16(ah[k0], bh, acc[t], 0, 0, 0);
            acc[t] = __builtin_amdgcn_mfma_f32_16x16x32_bf16(ah[k0], bl, acc[t], 0, 0, 0);
            acc[t] = __builtin_amdgcn_mfma_f32_16x16x32_bf16(al[k0], bh, acc[t], 0, 0, 0);
        }
    }

    // ---- epilogue: C/D layout col=lane&15, row=quad*4+reg (m89-verified)
#pragma unroll
    for (int reg = 0; reg < 4; reg++) {
        int gr = bm0 + wv * 16 + quad * 4 + reg;
        if (gr < n_rows) {
            float d = dis[gr];
#pragma unroll
            for (int t = 0; t < 4; t++) {
                int nt = ntBase + t;
                C[((size_t)nt * n_rows + gr) * CHK + col] = acc[t][reg] * d;
            }
        }
    }
}

// ---------------------------------------------------------------- CSR gather
// wave = (16 nodes, 1 chunk); chunk = blockIdx%8 pins the 3.2MB slice/XCD.
// Lane = (g = lane>>2 node slot 0..15, q = lane&3 float4 of the 64B row):
// one dwordx4 wave-load covers 16 full chunk rows (16 lines, 16B/lane).
// NO cross-lane reduce: lane's float4 acc IS the final (node, 4ch) sum.
__global__ __launch_bounds__(256) void gather_kernel(
    const int* __restrict__ rsp, const int* __restrict__ esrc,
    const float* __restrict__ dis, const float* __restrict__ hC,
    const float* __restrict__ bias, float* __restrict__ out, int n) {
    int c = blockIdx.x & 7;
    int wv = threadIdx.x >> 6;
    int lane = threadIdx.x & 63;
    int g = lane >> 2;    // node slot 0..15
    int q = lane & 3;     // float4 within the 16-channel row
    int i = (blockIdx.x >> 3) * 64 + wv * 16 + g;
    bool valid = (i < n);
    int iw = valid ? i : 0;
    const float4* __restrict__ h4 = (const float4*)(hC + (size_t)c * n * CHK);

    int beg = valid ? rsp[iw] : 0;
    int end = valid ? rsp[iw + 1] : 0;
    float4 acc = make_float4(0.f, 0.f, 0.f, 0.f);
    int j = beg;
    for (; j + 4 <= end; j += 4) {       // 4 independent esrc->h chains
        int s0 = esrc[j + 0];
        int s1 = esrc[j + 1];
        int s2 = esrc[j + 2];
        int s3 = esrc[j + 3];
        float4 v0 = h4[(size_t)s0 * 4 + q];
        float4 v1 = h4[(size_t)s1 * 4 + q];
        float4 v2 = h4[(size_t)s2 * 4 + q];
        float4 v3 = h4[(size_t)s3 * 4 + q];
        acc.x += v0.x; acc.y += v0.y; acc.z += v0.z; acc.w += v0.w;
        acc.x += v1.x; acc.y += v1.y; acc.z += v1.z; acc.w += v1.w;
        acc.x += v2.x; acc.y += v2.y; acc.z += v2.z; acc.w += v2.w;
        acc.x += v3.x; acc.y += v3.y; acc.z += v3.z; acc.w += v3.w;
    }
    for (; j < end; j++) {
        int s0 = esrc[j];
        float4 v0 = h4[(size_t)s0 * 4 + q];
        acc.x += v0.x; acc.y += v0.y; acc.z += v0.z; acc.w += v0.w;
    }
    if (valid) {
        float di = dis[iw];
        float4 bv = ((const float4*)bias)[c * 4 + q];
        float4 o;
        o.x = bv.x + di * acc.x;
        o.y = bv.y + di * acc.y;
        o.z = bv.z + di * acc.z;
        o.w = bv.w + di * acc.w;
        ((float4*)out)[(size_t)iw * 32 + c * 4 + q] = o;
    }
}

// ---------------------------------------------------------------- head
__global__ __launch_bounds__(256) void head_kernel(
    const float* __restrict__ A, const float* __restrict__ Wh,
    const float* __restrict__ bh, float* __restrict__ out, int n) {
    __shared__ float Ws[CH * NCLS];
    __shared__ float As[16][129];
    const int tid = threadIdx.x;
    const int n0 = blockIdx.x * 16;
#pragma unroll
    for (int i = 0; i < 8; i++) {
        int l = tid + i * 256;
        Ws[l] = Wh[l];
    }
#pragma unroll
    for (int i = 0; i < 8; i++) {
        int l = tid + i * 256;
        int r = l >> 7, c = l & 127;
        int gr = n0 + r;
        As[r][c] = (gr < n) ? fmaxf(A[(size_t)gr * CH + c], 0.0f) : 0.0f;
    }
    __syncthreads();
    int r = tid >> 4, c = tid & 15;
    float acc = bh[c];
#pragma unroll
    for (int k = 0; k < CH; k++) acc = fmaf(As[r][k], Ws[k * NCLS + c], acc);
    int gr = n0 + r;
    if (gr < n) out[(size_t)gr * NCLS + c] = acc;
}

// ---------------------------------------------------------------- launch
extern "C" void kernel_launch(void* const* d_in, const int* in_sizes, int n_in,
                              void* d_out, int out_size, void* d_ws, size_t ws_size,
                              hipStream_t stream) {
    const float* x  = (const float*)d_in[0];
    const int*   ei = (const int*)d_in[1];
    const float* W1 = (const float*)d_in[2];
    const float* b1 = (const float*)d_in[3];
    const float* W2 = (const float*)d_in[4];
    const float* b2 = (const float*)d_in[5];
    const float* Wh = (const float*)d_in[6];
    const float* bh = (const float*)d_in[7];
    float* out = (float*)d_out;

    const int n = in_sizes[0] / CH;   // 50000
    const int E = in_sizes[1] / 2;    // 800000
    const int* src = ei;
    const int* dst = ei + E;

    // workspace layout (Wt first: 4 x 16384 ushorts = 128 KB, keeps 16B align)
    ushort* w1hi = (ushort*)d_ws;                    // 16384
    ushort* w1lo = w1hi + CH * CH;
    ushort* w2hi = w1lo + CH * CH;
    ushort* w2lo = w2hi + CH * CH;
    float* dis  = (float*)(w2lo + CH * CH);          // n
    float* bufA = dis + n;                           // n*128  chunk-major h'
    float* bufB = bufA + (size_t)n * CH;             // n*128  row-major
    int* cnt    = (int*)(bufB + (size_t)n * CH);     // n
    int* rsp    = cnt + n;                           // n+1 (CSR row starts)
    int* cursor = rsp + n + 1;                       // n
    int* bsum   = cursor + n;                        // up to 256
    int* esrc   = bsum + 256;                        // E + n (self-loops)

    const int B = 256;
    const int nb_scan = (n + SCAN_IPB - 1) / SCAN_IPB;   // 49
    const int partGrid = 512;   // 8 partitions x 64 blocks, blockIdx&7 = XCD

    // ---- CSR build (XCD-partitioned) + normalization + W conversion
    zero_int_kernel<<<(n + B - 1) / B, B, 0, stream>>>(cnt, n);
    count_kernel<<<partGrid, B, 0, stream>>>(dst, cnt, E, n);
    dis_kernel<<<(n + B - 1) / B, B, 0, stream>>>(cnt, dis, n);
    scan1_kernel<<<nb_scan, B, 0, stream>>>(cnt, rsp, bsum, n);
    scan2_kernel<<<1, B, 0, stream>>>(bsum, nb_scan);
    scan3_kernel<<<(n + B - 1) / B, B, 0, stream>>>(rsp, cursor, bsum, cnt, esrc, n);
    fill_kernel<<<partGrid, B, 0, stream>>>(src, dst, cursor, esrc, E, n);
    convw_kernel<<<(CH * CH + B - 1) / B, B, 0, stream>>>(W1, w1hi, w1lo);
    convw_kernel<<<(CH * CH + B - 1) / B, B, 0, stream>>>(W2, w2hi, w2lo);

    const dim3 gemmGrid((n + 63) / 64, 2);
    const int gatherGrid = NCHUNK * ((n + 63) / 64);   // 64 nodes/block/chunk

    // layer 1
    gemm_mfma<false><<<gemmGrid, B, 0, stream>>>(x, w1hi, w1lo, dis, bufA, n);
    gather_kernel<<<gatherGrid, B, 0, stream>>>(rsp, esrc, dis, bufA, b1, bufB, n);
    // layer 2
    gemm_mfma<true><<<gemmGrid, B, 0, stream>>>(bufB, w2hi, w2lo, dis, bufA, n);
    gather_kernel<<<gatherGrid, B, 0, stream>>>(rsp, esrc, dis, bufA, b2, bufB, n);
    // head
    head_kernel<<<(n + 15) / 16, B, 0, stream>>>(bufB, Wh, bh, out, n);
}

// Round 11
// 355.365 us; speedup vs baseline: 1.4756x; 1.0458x over previous
//
#include <hip/hip_runtime.h>

#define CH 128
#define NCLS 16
#define CHK 16          // channels per chunk
#define NCHUNK 8        // 8 chunks of 16 == 128 channels, one per XCD
#define SCAN_IPB 1024   // items per block in scan pass 1

typedef __attribute__((ext_vector_type(8))) short bf16x8;
typedef __attribute__((ext_vector_type(4))) float f32x4;

__device__ inline ushort f2bf(float f) {        // RTNE fp32 -> bf16 bits
    unsigned u = __float_as_uint(f);
    unsigned r = u + 0x7fffu + ((u >> 16) & 1u);
    return (ushort)(r >> 16);
}
__device__ inline float bf2f(ushort b) {
    return __uint_as_float(((unsigned)b) << 16);
}

// ---------------------------------------------------------------- prep (fused)
// blocks [0,64): convert+transpose W1; [64,128): W2; [128,128+nb): zero cnt;
// last block: zero the dummy rows (row n of each chunk) of bufA.
__global__ __launch_bounds__(256) void prep_kernel(
    const float* __restrict__ W1, const float* __restrict__ W2,
    ushort* __restrict__ w1hi, ushort* __restrict__ w1lo,
    ushort* __restrict__ w2hi, ushort* __restrict__ w2lo,
    int* __restrict__ cnt, float* __restrict__ bufA, int n, int nbz) {
    int b = blockIdx.x, tid = threadIdx.x;
    if (b < 128) {
        const float* W = (b < 64) ? W1 : W2;
        ushort* Whi = (b < 64) ? w1hi : w2hi;
        ushort* Wlo = (b < 64) ? w1lo : w2lo;
        int t = ((b & 63) << 8) + tid;
        int k = t >> 7, nn = t & 127;
        float v = W[t];
        ushort h = f2bf(v);
        Whi[nn * CH + k] = h;
        Wlo[nn * CH + k] = f2bf(v - bf2f(h));
    } else if (b < 128 + nbz) {
        int i = (b - 128) * 256 + tid;
        if (i < n) cnt[i] = 0;
    } else {
        if (tid < NCHUNK * CHK) {
            int c = tid >> 4, ch = tid & 15;
            bufA[((size_t)c * (n + 1) + n) * CHK + ch] = 0.0f;
        }
    }
}

// XCD-partitioned degree count: partition p = blockIdx&7 owns dst range.
__global__ void count_kernel(const int* __restrict__ dst,
                             int* __restrict__ cnt, int E, int n) {
    int part = blockIdx.x & 7;
    int npp = (n + 7) >> 3;
    int lo = part * npp;
    int hi = min(n, lo + npp);
    int stride = (gridDim.x >> 3) * blockDim.x;
    for (int e = (blockIdx.x >> 3) * blockDim.x + threadIdx.x; e < E; e += stride) {
        int d = dst[e];
        if (d >= lo && d < hi) atomicAdd(&cnt[d], 1);
    }
}

// ---------------------------------------------------------------- scan (CSR)
// scan over PADDED counts round8(cnt+1); also emits dis = rsqrt(cnt+1).
__global__ __launch_bounds__(256) void scan1_kernel(
    const int* __restrict__ cnt, int* __restrict__ rsp,
    int* __restrict__ bsum, float* __restrict__ dis, int n) {
    __shared__ int lds[256];
    int t = threadIdx.x, b = blockIdx.x;
    int base = b * SCAN_IPB + t * 4;
    int v[4];
    int s = 0;
#pragma unroll
    for (int k = 0; k < 4; k++) {
        if (base + k < n) {
            int c = cnt[base + k];
            v[k] = (c + 8) & ~7;        // round8(c+1)
            dis[base + k] = rsqrtf((float)c + 1.0f);
        } else v[k] = 0;
        s += v[k];
    }
    lds[t] = s;
    __syncthreads();
    for (int off = 1; off < 256; off <<= 1) {
        int x = (t >= off) ? lds[t - off] : 0;
        __syncthreads();
        lds[t] += x;
        __syncthreads();
    }
    int incl = lds[t];
    int run = incl - s;   // exclusive across threads
#pragma unroll
    for (int k = 0; k < 4; k++) {
        if (base + k < n) rsp[base + k] = run;
        run += v[k];
    }
    if (t == 255) bsum[b] = incl;
}

__global__ __launch_bounds__(256) void scan2_kernel(int* __restrict__ bsum, int nb) {
    __shared__ int lds[256];
    int t = threadIdx.x;
    int s = (t < nb) ? bsum[t] : 0;
    lds[t] = s;
    __syncthreads();
    for (int off = 1; off < 256; off <<= 1) {
        int x = (t >= off) ? lds[t - off] : 0;
        __syncthreads();
        lds[t] += x;
        __syncthreads();
    }
    if (t < nb) bsum[t] = lds[t] - s;   // exclusive
}

// finalize rsp, init cursor, write self-edge + pad entries (dummy row n)
__global__ void scan3_kernel(int* __restrict__ rsp, int* __restrict__ cursor,
                             const int* __restrict__ bsum,
                             const int* __restrict__ cnt,
                             ushort* __restrict__ esrc, int n) {
    int i = blockIdx.x * blockDim.x + threadIdx.x;
    if (i >= n) return;
    int v = rsp[i] + bsum[i >> 10];   // >>10 == /SCAN_IPB
    rsp[i] = v;
    cursor[i] = v + 1;                // slot v holds the self-edge
    esrc[v] = (ushort)i;              // self-loop as a real edge
    int ci = cnt[i];
    int pc = (ci + 8) & ~7;
    for (int p = v + 1 + ci; p < v + pc; p++) esrc[p] = (ushort)n;  // pads
    if (i == n - 1) rsp[n] = v + pc;
}

// XCD-partitioned CSR fill (local-L2 atomics + once-written esrc lines)
__global__ void fill_kernel(const int* __restrict__ src, const int* __restrict__ dst,
                            int* __restrict__ cursor, ushort* __restrict__ esrc,
                            int E, int n) {
    int part = blockIdx.x & 7;
    int npp = (n + 7) >> 3;
    int lo = part * npp;
    int hi = min(n, lo + npp);
    int stride = (gridDim.x >> 3) * blockDim.x;
    for (int e = (blockIdx.x >> 3) * blockDim.x + threadIdx.x; e < E; e += stride) {
        int d = dst[e];
        if (d >= lo && d < hi) {
            int p = atomicAdd(&cursor[d], 1);
            esrc[p] = (ushort)src[e];
        }
    }
}

// ---------------------------------------------------------------- MFMA GEMM v2
// C[n_rows x 128] = relu?(A) @ W via bf16 hi/lo split (hi*hi + hi*lo + lo*hi).
// NO LDS, NO barrier. C chunk-major with pitch (n_rows+1), PRE-SCALED by dis.
template <bool RELU_IN>
__global__ __launch_bounds__(256, 4) void gemm_mfma(
    const float* __restrict__ A, const ushort* __restrict__ Bthi,
    const ushort* __restrict__ Btlo, const float* __restrict__ dis,
    float* __restrict__ C, int n_rows) {
    const int tid = threadIdx.x;
    const int bm0 = blockIdx.x * 64;
    const int wv = tid >> 6;
    const int lane = tid & 63;
    const int col = lane & 15;     // A row-in-frag / B col / C col
    const int quad = lane >> 4;    // k-block for A/B; row-quad for C
    const int arow = bm0 + wv * 16 + col;    // this lane's A row
    const bool av = (arow < n_rows);
    const float* __restrict__ Arow = A + (size_t)arow * CH;

    bf16x8 ah[4], al[4];
#pragma unroll
    for (int k0 = 0; k0 < 4; k0++) {
        const int kb = k0 * 32 + quad * 8;
        float4 f0 = av ? *(const float4*)&Arow[kb]     : make_float4(0.f, 0.f, 0.f, 0.f);
        float4 f1 = av ? *(const float4*)&Arow[kb + 4] : make_float4(0.f, 0.f, 0.f, 0.f);
        if (RELU_IN) {
            f0.x = fmaxf(f0.x, 0.f); f0.y = fmaxf(f0.y, 0.f);
            f0.z = fmaxf(f0.z, 0.f); f0.w = fmaxf(f0.w, 0.f);
            f1.x = fmaxf(f1.x, 0.f); f1.y = fmaxf(f1.y, 0.f);
            f1.z = fmaxf(f1.z, 0.f); f1.w = fmaxf(f1.w, 0.f);
        }
        float fa[8] = {f0.x, f0.y, f0.z, f0.w, f1.x, f1.y, f1.z, f1.w};
#pragma unroll
        for (int j = 0; j < 8; j++) {
            ushort h = f2bf(fa[j]);
            ah[k0][j] = (short)h;
            al[k0][j] = (short)f2bf(fa[j] - bf2f(h));
        }
    }

    const int ntBase = blockIdx.y * 4;
    f32x4 acc[4];
#pragma unroll
    for (int t = 0; t < 4; t++) acc[t] = (f32x4){0.f, 0.f, 0.f, 0.f};

#pragma unroll
    for (int t = 0; t < 4; t++) {
        const int nt = ntBase + t;
#pragma unroll
        for (int k0 = 0; k0 < 4; k0++) {
            const int kb = k0 * 32 + quad * 8;
            const int boff = (nt * 16 + col) * CH + kb;
            bf16x8 bh = *(const bf16x8*)&Bthi[boff];
            bf16x8 bl = *(const bf16x8*)&Btlo[boff];
            acc[t] = __builtin_amdgcn_mfma_f32_16x16x32_bf16(ah[k0], bh, acc[t], 0, 0, 0);
            acc[t] = __builtin_amdgcn_mfma_f32_16x16x32_bf16(ah[k0], bl, acc[t], 0, 0, 0);
            acc[t] = __builtin_amdgcn_mfma_f32_16x16x32_bf16(al[k0], bh, acc[t], 0, 0, 0);
        }
    }

    // epilogue: C/D layout col=lane&15, row=quad*4+reg (m89-verified)
#pragma unroll
    for (int reg = 0; reg < 4; reg++) {
        int gr = bm0 + wv * 16 + quad * 4 + reg;
        if (gr < n_rows) {
            float d = dis[gr];
#pragma unroll
            for (int t = 0; t < 4; t++) {
                int nt = ntBase + t;
                C[((size_t)nt * (n_rows + 1) + gr) * CHK + col] = acc[t][reg] * d;
            }
        }
    }
}

// ---------------------------------------------------------------- CSR gather
// wave = (16 nodes, 1 chunk); chunk = blockIdx%8 pins the 3.2MB slice/XCD.
// Edge lists padded to x8 (pads -> zero row n). Lane = (g=lane>>2 node slot,
// q=lane&3 float4 of the 64B row). Per 8-edge iter: two broadcast ushort4
// index loads + 8 independent h-row loads (128 outstanding lines per wave).
__global__ __launch_bounds__(256) void gather_kernel(
    const int* __restrict__ rsp, const ushort* __restrict__ esrc,
    const float* __restrict__ dis, const float* __restrict__ hC,
    const float* __restrict__ bias, float* __restrict__ out, int n) {
    int c = blockIdx.x & 7;
    int wv = threadIdx.x >> 6;
    int lane = threadIdx.x & 63;
    int g = lane >> 2;    // node slot 0..15
    int q = lane & 3;     // float4 within the 16-channel row
    int i = (blockIdx.x >> 3) * 64 + wv * 16 + g;
    bool valid = (i < n);
    int iw = valid ? i : 0;
    const float4* __restrict__ h4 = (const float4*)(hC + (size_t)c * (n + 1) * CHK);

    int beg = valid ? rsp[iw] : 0;
    int end = valid ? rsp[iw + 1] : 0;
    float4 acc = make_float4(0.f, 0.f, 0.f, 0.f);
    for (int j = beg; j < end; j += 8) {   // beg/end are multiples of 8
        ushort4 e0 = *(const ushort4*)&esrc[j];
        ushort4 e1 = *(const ushort4*)&esrc[j + 4];
        float4 v0 = h4[(size_t)e0.x * 4 + q];
        float4 v1 = h4[(size_t)e0.y * 4 + q];
        float4 v2 = h4[(size_t)e0.z * 4 + q];
        float4 v3 = h4[(size_t)e0.w * 4 + q];
        float4 v4 = h4[(size_t)e1.x * 4 + q];
        float4 v5 = h4[(size_t)e1.y * 4 + q];
        float4 v6 = h4[(size_t)e1.z * 4 + q];
        float4 v7 = h4[(size_t)e1.w * 4 + q];
        acc.x += v0.x; acc.y += v0.y; acc.z += v0.z; acc.w += v0.w;
        acc.x += v1.x; acc.y += v1.y; acc.z += v1.z; acc.w += v1.w;
        acc.x += v2.x; acc.y += v2.y; acc.z += v2.z; acc.w += v2.w;
        acc.x += v3.x; acc.y += v3.y; acc.z += v3.z; acc.w += v3.w;
        acc.x += v4.x; acc.y += v4.y; acc.z += v4.z; acc.w += v4.w;
        acc.x += v5.x; acc.y += v5.y; acc.z += v5.z; acc.w += v5.w;
        acc.x += v6.x; acc.y += v6.y; acc.z += v6.z; acc.w += v6.w;
        acc.x += v7.x; acc.y += v7.y; acc.z += v7.z; acc.w += v7.w;
    }
    if (valid) {
        float di = dis[iw];
        float4 bv = ((const float4*)bias)[c * 4 + q];
        float4 o;
        o.x = bv.x + di * acc.x;
        o.y = bv.y + di * acc.y;
        o.z = bv.z + di * acc.z;
        o.w = bv.w + di * acc.w;
        ((float4*)out)[(size_t)iw * 32 + c * 4 + q] = o;
    }
}

// ---------------------------------------------------------------- head
__global__ __launch_bounds__(256) void head_kernel(
    const float* __restrict__ A, const float* __restrict__ Wh,
    const float* __restrict__ bh, float* __restrict__ out, int n) {
    __shared__ float Ws[CH * NCLS];
    __shared__ float As[16][129];
    const int tid = threadIdx.x;
    const int n0 = blockIdx.x * 16;
#pragma unroll
    for (int i = 0; i < 8; i++) {
        int l = tid + i * 256;
        Ws[l] = Wh[l];
    }
#pragma unroll
    for (int i = 0; i < 8; i++) {
        int l = tid + i * 256;
        int r = l >> 7, c = l & 127;
        int gr = n0 + r;
        As[r][c] = (gr < n) ? fmaxf(A[(size_t)gr * CH + c], 0.0f) : 0.0f;
    }
    __syncthreads();
    int r = tid >> 4, c = tid & 15;
    float acc = bh[c];
#pragma unroll
    for (int k = 0; k < CH; k++) acc = fmaf(As[r][k], Ws[k * NCLS + c], acc);
    int gr = n0 + r;
    if (gr < n) out[(size_t)gr * NCLS + c] = acc;
}

// ---------------------------------------------------------------- launch
extern "C" void kernel_launch(void* const* d_in, const int* in_sizes, int n_in,
                              void* d_out, int out_size, void* d_ws, size_t ws_size,
                              hipStream_t stream) {
    const float* x  = (const float*)d_in[0];
    const int*   ei = (const int*)d_in[1];
    const float* W1 = (const float*)d_in[2];
    const float* b1 = (const float*)d_in[3];
    const float* W2 = (const float*)d_in[4];
    const float* b2 = (const float*)d_in[5];
    const float* Wh = (const float*)d_in[6];
    const float* bh = (const float*)d_in[7];
    float* out = (float*)d_out;

    const int n = in_sizes[0] / CH;   // 50000
    const int E = in_sizes[1] / 2;    // 800000
    const int* src = ei;
    const int* dst = ei + E;

    // workspace layout
    ushort* w1hi = (ushort*)d_ws;                    // 16384 each
    ushort* w1lo = w1hi + CH * CH;
    ushort* w2hi = w1lo + CH * CH;
    ushort* w2lo = w2hi + CH * CH;
    float* dis  = (float*)(w2lo + CH * CH);          // n
    float* bufA = dis + n;                           // (n+1)*128 chunk-major h'
    float* bufB = bufA + (size_t)(n + 1) * CH;       // n*128 row-major
    int* cnt    = (int*)(bufB + (size_t)n * CH);     // n
    int* rsp    = cnt + n;                           // n+1 (padded CSR starts)
    int* cursor = rsp + n + 1;                       // n
    int* bsum   = cursor + n;                        // up to 256
    ushort* esrc = (ushort*)(bsum + 256);            // <= E + 8n padded edges

    const int B = 256;
    const int nb_scan = (n + SCAN_IPB - 1) / SCAN_IPB;   // 49
    const int nbz = (n + B - 1) / B;                     // cnt-zero blocks
    const int partGrid = 512;   // 8 partitions x 64 blocks, blockIdx&7 = XCD

    // ---- prep (W conversion + cnt zero + dummy-row zero), then CSR build
    prep_kernel<<<128 + nbz + 1, B, 0, stream>>>(W1, W2, w1hi, w1lo, w2hi, w2lo,
                                                 cnt, bufA, n, nbz);
    count_kernel<<<partGrid, B, 0, stream>>>(dst, cnt, E, n);
    scan1_kernel<<<nb_scan, B, 0, stream>>>(cnt, rsp, bsum, dis, n);
    scan2_kernel<<<1, B, 0, stream>>>(bsum, nb_scan);
    scan3_kernel<<<(n + B - 1) / B, B, 0, stream>>>(rsp, cursor, bsum, cnt, esrc, n);
    fill_kernel<<<partGrid, B, 0, stream>>>(src, dst, cursor, esrc, E, n);

    const dim3 gemmGrid((n + 63) / 64, 2);
    const int gatherGrid = NCHUNK * ((n + 63) / 64);   // 64 nodes/block/chunk

    // layer 1
    gemm_mfma<false><<<gemmGrid, B, 0, stream>>>(x, w1hi, w1lo, dis, bufA, n);
    gather_kernel<<<gatherGrid, B, 0, stream>>>(rsp, esrc, dis, bufA, b1, bufB, n);
    // layer 2
    gemm_mfma<true><<<gemmGrid, B, 0, stream>>>(bufB, w2hi, w2lo, dis, bufA, n);
    gather_kernel<<<gatherGrid, B, 0, stream>>>(rsp, esrc, dis, bufA, b2, bufB, n);
    // head
    head_kernel<<<(n + 15) / 16, B, 0, stream>>>(bufB, Wh, bh, out, n);
}

// Round 12
// 321.146 us; speedup vs baseline: 1.6328x; 1.1066x over previous
//
#include <hip/hip_runtime.h>

#define CH 128
#define NCLS 16
#define CHK 16          // channels per chunk
#define NCHUNK 8        // 8 chunks of 16 == 128 channels, one per XCD
#define SCAN_IPB 1024   // items per block in scan pass 1

typedef __attribute__((ext_vector_type(8))) short bf16x8;
typedef __attribute__((ext_vector_type(4))) float f32x4;

__device__ inline ushort f2bf(float f) {        // RTNE fp32 -> bf16 bits
    unsigned u = __float_as_uint(f);
    unsigned r = u + 0x7fffu + ((u >> 16) & 1u);
    return (ushort)(r >> 16);
}
__device__ inline float bf2f(ushort b) {
    return __uint_as_float(((unsigned)b) << 16);
}

// ---------------------------------------------------------------- prep (fused)
__global__ __launch_bounds__(256) void prep_kernel(
    const float* __restrict__ W1, const float* __restrict__ W2,
    ushort* __restrict__ w1hi, ushort* __restrict__ w1lo,
    ushort* __restrict__ w2hi, ushort* __restrict__ w2lo,
    int* __restrict__ cnt, float* __restrict__ bufA, int n, int nbz) {
    int b = blockIdx.x, tid = threadIdx.x;
    if (b < 128) {
        const float* W = (b < 64) ? W1 : W2;
        ushort* Whi = (b < 64) ? w1hi : w2hi;
        ushort* Wlo = (b < 64) ? w1lo : w2lo;
        int t = ((b & 63) << 8) + tid;
        int k = t >> 7, nn = t & 127;
        float v = W[t];
        ushort h = f2bf(v);
        Whi[nn * CH + k] = h;
        Wlo[nn * CH + k] = f2bf(v - bf2f(h));
    } else if (b < 128 + nbz) {
        int i = (b - 128) * 256 + tid;
        if (i < n) cnt[i] = 0;
    } else {
        if (tid < NCHUNK * CHK) {
            int c = tid >> 4, ch = tid & 15;
            bufA[((size_t)c * (n + 1) + n) * CHK + ch] = 0.0f;
        }
    }
}

// XCD-partitioned degree count
__global__ void count_kernel(const int* __restrict__ dst,
                             int* __restrict__ cnt, int E, int n) {
    int part = blockIdx.x & 7;
    int npp = (n + 7) >> 3;
    int lo = part * npp;
    int hi = min(n, lo + npp);
    int stride = (gridDim.x >> 3) * blockDim.x;
    for (int e = (blockIdx.x >> 3) * blockDim.x + threadIdx.x; e < E; e += stride) {
        int d = dst[e];
        if (d >= lo && d < hi) atomicAdd(&cnt[d], 1);
    }
}

// ---------------------------------------------------------------- scan (CSR)
__global__ __launch_bounds__(256) void scan1_kernel(
    const int* __restrict__ cnt, int* __restrict__ rsp,
    int* __restrict__ bsum, float* __restrict__ dis, int n) {
    __shared__ int lds[256];
    int t = threadIdx.x, b = blockIdx.x;
    int base = b * SCAN_IPB + t * 4;
    int v[4];
    int s = 0;
#pragma unroll
    for (int k = 0; k < 4; k++) {
        if (base + k < n) {
            int c = cnt[base + k];
            v[k] = (c + 8) & ~7;        // round8(c+1)
            dis[base + k] = rsqrtf((float)c + 1.0f);
        } else v[k] = 0;
        s += v[k];
    }
    lds[t] = s;
    __syncthreads();
    for (int off = 1; off < 256; off <<= 1) {
        int x = (t >= off) ? lds[t - off] : 0;
        __syncthreads();
        lds[t] += x;
        __syncthreads();
    }
    int incl = lds[t];
    int run = incl - s;   // exclusive across threads
#pragma unroll
    for (int k = 0; k < 4; k++) {
        if (base + k < n) rsp[base + k] = run;
        run += v[k];
    }
    if (t == 255) bsum[b] = incl;
}

__global__ __launch_bounds__(256) void scan2_kernel(int* __restrict__ bsum, int nb) {
    __shared__ int lds[256];
    int t = threadIdx.x;
    int s = (t < nb) ? bsum[t] : 0;
    lds[t] = s;
    __syncthreads();
    for (int off = 1; off < 256; off <<= 1) {
        int x = (t >= off) ? lds[t - off] : 0;
        __syncthreads();
        lds[t] += x;
        __syncthreads();
    }
    if (t < nb) bsum[t] = lds[t] - s;   // exclusive
}

__global__ void scan3_kernel(int* __restrict__ rsp, int* __restrict__ cursor,
                             const int* __restrict__ bsum,
                             const int* __restrict__ cnt,
                             ushort* __restrict__ esrc, int n) {
    int i = blockIdx.x * blockDim.x + threadIdx.x;
    if (i >= n) return;
    int v = rsp[i] + bsum[i >> 10];   // >>10 == /SCAN_IPB
    rsp[i] = v;
    cursor[i] = v + 1;                // slot v holds the self-edge
    esrc[v] = (ushort)i;              // self-loop as a real edge
    int ci = cnt[i];
    int pc = (ci + 8) & ~7;
    for (int p = v + 1 + ci; p < v + pc; p++) esrc[p] = (ushort)n;  // pads
    if (i == n - 1) rsp[n] = v + pc;
}

// XCD-partitioned CSR fill
__global__ void fill_kernel(const int* __restrict__ src, const int* __restrict__ dst,
                            int* __restrict__ cursor, ushort* __restrict__ esrc,
                            int E, int n) {
    int part = blockIdx.x & 7;
    int npp = (n + 7) >> 3;
    int lo = part * npp;
    int hi = min(n, lo + npp);
    int stride = (gridDim.x >> 3) * blockDim.x;
    for (int e = (blockIdx.x >> 3) * blockDim.x + threadIdx.x; e < E; e += stride) {
        int d = dst[e];
        if (d >= lo && d < hi) {
            int p = atomicAdd(&cursor[d], 1);
            esrc[p] = (ushort)src[e];
        }
    }
}

// ---------------------------------------------------------------- MFMA GEMM v3
// C = relu?(A) @ W, bf16 hi/lo split. Wave = 64 rows x 4 N-tiles: per k0,
// 4 A-frags (hi/lo) are loaded once and each B hi/lo pair feeds 12 MFMAs --
// 4x fewer B-vmem per unit work than v2 (TA line-throughput was the wall).
// C chunk-major with pitch (n_rows+1), rows PRE-SCALED by dis[row].
template <bool RELU_IN>
__global__ __launch_bounds__(256, 2) void gemm_mfma(
    const float* __restrict__ A, const ushort* __restrict__ Bthi,
    const ushort* __restrict__ Btlo, const float* __restrict__ dis,
    float* __restrict__ C, int n_rows) {
    const int tid = threadIdx.x;
    const int bm0 = blockIdx.x * 256;        // block covers 256 rows
    const int wv = tid >> 6;
    const int lane = tid & 63;
    const int col = lane & 15;     // A row-in-frag / B col / C col
    const int quad = lane >> 4;    // k-block for A/B; row-quad for C
    const int rbase = bm0 + wv * 64 + col;   // wave rows: rbase + m*16
    const int ntBase = blockIdx.y * 4;

    f32x4 acc[4][4];   // [m][nt]
#pragma unroll
    for (int m = 0; m < 4; m++)
#pragma unroll
        for (int t = 0; t < 4; t++) acc[m][t] = (f32x4){0.f, 0.f, 0.f, 0.f};

#pragma unroll
    for (int k0 = 0; k0 < 4; k0++) {
        const int kb = k0 * 32 + quad * 8;
        bf16x8 ah[4], al[4];
#pragma unroll
        for (int m = 0; m < 4; m++) {
            int arow = rbase + m * 16;
            bool av = (arow < n_rows);
            const float* __restrict__ Ap = A + (size_t)arow * CH + kb;
            float4 f0 = av ? *(const float4*)Ap       : make_float4(0.f, 0.f, 0.f, 0.f);
            float4 f1 = av ? *(const float4*)(Ap + 4) : make_float4(0.f, 0.f, 0.f, 0.f);
            if (RELU_IN) {
                f0.x = fmaxf(f0.x, 0.f); f0.y = fmaxf(f0.y, 0.f);
                f0.z = fmaxf(f0.z, 0.f); f0.w = fmaxf(f0.w, 0.f);
                f1.x = fmaxf(f1.x, 0.f); f1.y = fmaxf(f1.y, 0.f);
                f1.z = fmaxf(f1.z, 0.f); f1.w = fmaxf(f1.w, 0.f);
            }
            float fa[8] = {f0.x, f0.y, f0.z, f0.w, f1.x, f1.y, f1.z, f1.w};
#pragma unroll
            for (int j = 0; j < 8; j++) {
                ushort h = f2bf(fa[j]);
                ah[m][j] = (short)h;
                al[m][j] = (short)f2bf(fa[j] - bf2f(h));
            }
        }
#pragma unroll
        for (int t = 0; t < 4; t++) {
            const int boff = ((ntBase + t) * 16 + col) * CH + kb;
            bf16x8 bh = *(const bf16x8*)&Bthi[boff];
            bf16x8 bl = *(const bf16x8*)&Btlo[boff];
#pragma unroll
            for (int m = 0; m < 4; m++) {
                acc[m][t] = __builtin_amdgcn_mfma_f32_16x16x32_bf16(ah[m], bh, acc[m][t], 0, 0, 0);
                acc[m][t] = __builtin_amdgcn_mfma_f32_16x16x32_bf16(ah[m], bl, acc[m][t], 0, 0, 0);
                acc[m][t] = __builtin_amdgcn_mfma_f32_16x16x32_bf16(al[m], bh, acc[m][t], 0, 0, 0);
            }
        }
    }

    // epilogue: C/D layout col=lane&15, row=quad*4+reg (m89-verified)
#pragma unroll
    for (int m = 0; m < 4; m++) {
#pragma unroll
        for (int reg = 0; reg < 4; reg++) {
            int gr = bm0 + wv * 64 + m * 16 + quad * 4 + reg;
            if (gr < n_rows) {
                float d = dis[gr];
#pragma unroll
                for (int t = 0; t < 4; t++) {
                    int nt = ntBase + t;
                    C[((size_t)nt * (n_rows + 1) + gr) * CHK + col] = acc[m][t][reg] * d;
                }
            }
        }
    }
}

// ---------------------------------------------------------------- CSR gather
// wave = (16 nodes, 1 chunk); chunk = blockIdx%8 pins the 3.2MB slice/XCD.
// Edge lists padded to x8 (pads -> zero row n). Lane = (g=lane>>2 node slot,
// q=lane&3 float4 of the 64B row). Per 8-edge iter: two broadcast ushort4
// index loads + 8 independent h-row loads.
__global__ __launch_bounds__(256) void gather_kernel(
    const int* __restrict__ rsp, const ushort* __restrict__ esrc,
    const float* __restrict__ dis, const float* __restrict__ hC,
    const float* __restrict__ bias, float* __restrict__ out, int n) {
    int c = blockIdx.x & 7;
    int wv = threadIdx.x >> 6;
    int lane = threadIdx.x & 63;
    int g = lane >> 2;    // node slot 0..15
    int q = lane & 3;     // float4 within the 16-channel row
    int i = (blockIdx.x >> 3) * 64 + wv * 16 + g;
    bool valid = (i < n);
    int iw = valid ? i : 0;
    const float4* __restrict__ h4 = (const float4*)(hC + (size_t)c * (n + 1) * CHK);

    int beg = valid ? rsp[iw] : 0;
    int end = valid ? rsp[iw + 1] : 0;
    float4 acc = make_float4(0.f, 0.f, 0.f, 0.f);
    for (int j = beg; j < end; j += 8) {   // beg/end are multiples of 8
        ushort4 e0 = *(const ushort4*)&esrc[j];
        ushort4 e1 = *(const ushort4*)&esrc[j + 4];
        float4 v0 = h4[(size_t)e0.x * 4 + q];
        float4 v1 = h4[(size_t)e0.y * 4 + q];
        float4 v2 = h4[(size_t)e0.z * 4 + q];
        float4 v3 = h4[(size_t)e0.w * 4 + q];
        float4 v4 = h4[(size_t)e1.x * 4 + q];
        float4 v5 = h4[(size_t)e1.y * 4 + q];
        float4 v6 = h4[(size_t)e1.z * 4 + q];
        float4 v7 = h4[(size_t)e1.w * 4 + q];
        acc.x += v0.x; acc.y += v0.y; acc.z += v0.z; acc.w += v0.w;
        acc.x += v1.x; acc.y += v1.y; acc.z += v1.z; acc.w += v1.w;
        acc.x += v2.x; acc.y += v2.y; acc.z += v2.z; acc.w += v2.w;
        acc.x += v3.x; acc.y += v3.y; acc.z += v3.z; acc.w += v3.w;
        acc.x += v4.x; acc.y += v4.y; acc.z += v4.z; acc.w += v4.w;
        acc.x += v5.x; acc.y += v5.y; acc.z += v5.z; acc.w += v5.w;
        acc.x += v6.x; acc.y += v6.y; acc.z += v6.z; acc.w += v6.w;
        acc.x += v7.x; acc.y += v7.y; acc.z += v7.z; acc.w += v7.w;
    }
    if (valid) {
        float di = dis[iw];
        float4 bv = ((const float4*)bias)[c * 4 + q];
        float4 o;
        o.x = bv.x + di * acc.x;
        o.y = bv.y + di * acc.y;
        o.z = bv.z + di * acc.z;
        o.w = bv.w + di * acc.w;
        ((float4*)out)[(size_t)iw * 32 + c * 4 + q] = o;
    }
}

// ---------------------------------------------------------------- head
__global__ __launch_bounds__(256) void head_kernel(
    const float* __restrict__ A, const float* __restrict__ Wh,
    const float* __restrict__ bh, float* __restrict__ out, int n) {
    __shared__ float Ws[CH * NCLS];
    __shared__ float As[16][129];
    const int tid = threadIdx.x;
    const int n0 = blockIdx.x * 16;
#pragma unroll
    for (int i = 0; i < 8; i++) {
        int l = tid + i * 256;
        Ws[l] = Wh[l];
    }
#pragma unroll
    for (int i = 0; i < 8; i++) {
        int l = tid + i * 256;
        int r = l >> 7, c = l & 127;
        int gr = n0 + r;
        As[r][c] = (gr < n) ? fmaxf(A[(size_t)gr * CH + c], 0.0f) : 0.0f;
    }
    __syncthreads();
    int r = tid >> 4, c = tid & 15;
    float acc = bh[c];
#pragma unroll
    for (int k = 0; k < CH; k++) acc = fmaf(As[r][k], Ws[k * NCLS + c], acc);
    int gr = n0 + r;
    if (gr < n) out[(size_t)gr * NCLS + c] = acc;
}

// ---------------------------------------------------------------- launch
extern "C" void kernel_launch(void* const* d_in, const int* in_sizes, int n_in,
                              void* d_out, int out_size, void* d_ws, size_t ws_size,
                              hipStream_t stream) {
    const float* x  = (const float*)d_in[0];
    const int*   ei = (const int*)d_in[1];
    const float* W1 = (const float*)d_in[2];
    const float* b1 = (const float*)d_in[3];
    const float* W2 = (const float*)d_in[4];
    const float* b2 = (const float*)d_in[5];
    const float* Wh = (const float*)d_in[6];
    const float* bh = (const float*)d_in[7];
    float* out = (float*)d_out;

    const int n = in_sizes[0] / CH;   // 50000
    const int E = in_sizes[1] / 2;    // 800000
    const int* src = ei;
    const int* dst = ei + E;

    // workspace layout
    ushort* w1hi = (ushort*)d_ws;                    // 16384 each
    ushort* w1lo = w1hi + CH * CH;
    ushort* w2hi = w1lo + CH * CH;
    ushort* w2lo = w2hi + CH * CH;
    float* dis  = (float*)(w2lo + CH * CH);          // n
    float* bufA = dis + n;                           // (n+1)*128 chunk-major h'
    float* bufB = bufA + (size_t)(n + 1) * CH;       // n*128 row-major
    int* cnt    = (int*)(bufB + (size_t)n * CH);     // n
    int* rsp    = cnt + n;                           // n+1 (padded CSR starts)
    int* cursor = rsp + n + 1;                       // n
    int* bsum   = cursor + n;                        // up to 256
    ushort* esrc = (ushort*)(bsum + 256);            // <= E + 8n padded edges

    const int B = 256;
    const int nb_scan = (n + SCAN_IPB - 1) / SCAN_IPB;   // 49
    const int nbz = (n + B - 1) / B;                     // cnt-zero blocks
    const int partGrid = 512;   // 8 partitions x 64 blocks, blockIdx&7 = XCD

    // ---- prep + CSR build
    prep_kernel<<<128 + nbz + 1, B, 0, stream>>>(W1, W2, w1hi, w1lo, w2hi, w2lo,
                                                 cnt, bufA, n, nbz);
    count_kernel<<<partGrid, B, 0, stream>>>(dst, cnt, E, n);
    scan1_kernel<<<nb_scan, B, 0, stream>>>(cnt, rsp, bsum, dis, n);
    scan2_kernel<<<1, B, 0, stream>>>(bsum, nb_scan);
    scan3_kernel<<<(n + B - 1) / B, B, 0, stream>>>(rsp, cursor, bsum, cnt, esrc, n);
    fill_kernel<<<partGrid, B, 0, stream>>>(src, dst, cursor, esrc, E, n);

    const dim3 gemmGrid((n + 255) / 256, 2);
    const int gatherGrid = NCHUNK * ((n + 63) / 64);   // 64 nodes/block/chunk

    // layer 1
    gemm_mfma<false><<<gemmGrid, B, 0, stream>>>(x, w1hi, w1lo, dis, bufA, n);
    gather_kernel<<<gatherGrid, B, 0, stream>>>(rsp, esrc, dis, bufA, b1, bufB, n);
    // layer 2
    gemm_mfma<true><<<gemmGrid, B, 0, stream>>>(bufB, w2hi, w2lo, dis, bufA, n);
    gather_kernel<<<gatherGrid, B, 0, stream>>>(rsp, esrc, dis, bufA, b2, bufB, n);
    // head
    head_kernel<<<(n + 15) / 16, B, 0, stream>>>(bufB, Wh, bh, out, n);
}

// Round 13
// 316.344 us; speedup vs baseline: 1.6576x; 1.0152x over previous
//
#include <hip/hip_runtime.h>

#define CH 128
#define NCLS 16
#define CHK 16          // channels per chunk
#define NCHUNK 8        // 8 chunks of 16 == 128 channels, one per XCD
#define SCAN_IPB 1024   // items per block in scan pass 1

typedef __attribute__((ext_vector_type(8))) short bf16x8;
typedef __attribute__((ext_vector_type(4))) float f32x4;

__device__ inline ushort f2bf(float f) {        // RTNE fp32 -> bf16 bits
    unsigned u = __float_as_uint(f);
    unsigned r = u + 0x7fffu + ((u >> 16) & 1u);
    return (ushort)(r >> 16);
}
__device__ inline float bf2f(ushort b) {
    return __uint_as_float(((unsigned)b) << 16);
}

// ---------------------------------------------------------------- prep (fused)
__global__ __launch_bounds__(256) void prep_kernel(
    const float* __restrict__ W1, const float* __restrict__ W2,
    ushort* __restrict__ w1hi, ushort* __restrict__ w1lo,
    ushort* __restrict__ w2hi, ushort* __restrict__ w2lo,
    int* __restrict__ cnt, float* __restrict__ bufA, int n, int nbz) {
    int b = blockIdx.x, tid = threadIdx.x;
    if (b < 128) {
        const float* W = (b < 64) ? W1 : W2;
        ushort* Whi = (b < 64) ? w1hi : w2hi;
        ushort* Wlo = (b < 64) ? w1lo : w2lo;
        int t = ((b & 63) << 8) + tid;
        int k = t >> 7, nn = t & 127;
        float v = W[t];
        ushort h = f2bf(v);
        Whi[nn * CH + k] = h;
        Wlo[nn * CH + k] = f2bf(v - bf2f(h));
    } else if (b < 128 + nbz) {
        int i = (b - 128) * 256 + tid;
        if (i < n) cnt[i] = 0;
    } else {
        if (tid < NCHUNK * CHK) {
            int c = tid >> 4, ch = tid & 15;
            bufA[((size_t)c * (n + 1) + n) * CHK + ch] = 0.0f;
        }
    }
}

// XCD-partitioned degree count; grid = 8 partitions x 256 blocks (full machine)
__global__ __launch_bounds__(256) void count_kernel(
    const int* __restrict__ dst, int* __restrict__ cnt, int E, int n) {
    int part = blockIdx.x & 7;
    int npp = (n + 7) >> 3;
    int lo = part * npp;
    int hi = min(n, lo + npp);
    int stride = (gridDim.x >> 3) * blockDim.x;
    for (int e = (blockIdx.x >> 3) * blockDim.x + threadIdx.x; e < E; e += stride) {
        int d = dst[e];
        if (d >= lo && d < hi) atomicAdd(&cnt[d], 1);
    }
}

// ---------------------------------------------------------------- scan (CSR)
__global__ __launch_bounds__(256) void scan1_kernel(
    const int* __restrict__ cnt, int* __restrict__ rsp,
    int* __restrict__ bsum, float* __restrict__ dis, int n) {
    __shared__ int lds[256];
    int t = threadIdx.x, b = blockIdx.x;
    int base = b * SCAN_IPB + t * 4;
    int v[4];
    int s = 0;
#pragma unroll
    for (int k = 0; k < 4; k++) {
        if (base + k < n) {
            int c = cnt[base + k];
            v[k] = (c + 8) & ~7;        // round8(c+1)
            dis[base + k] = rsqrtf((float)c + 1.0f);
        } else v[k] = 0;
        s += v[k];
    }
    lds[t] = s;
    __syncthreads();
    for (int off = 1; off < 256; off <<= 1) {
        int x = (t >= off) ? lds[t - off] : 0;
        __syncthreads();
        lds[t] += x;
        __syncthreads();
    }
    int incl = lds[t];
    int run = incl - s;   // exclusive across threads
#pragma unroll
    for (int k = 0; k < 4; k++) {
        if (base + k < n) rsp[base + k] = run;
        run += v[k];
    }
    if (t == 255) bsum[b] = incl;
}

__global__ __launch_bounds__(256) void scan2_kernel(int* __restrict__ bsum, int nb) {
    __shared__ int lds[256];
    int t = threadIdx.x;
    int s = (t < nb) ? bsum[t] : 0;
    lds[t] = s;
    __syncthreads();
    for (int off = 1; off < 256; off <<= 1) {
        int x = (t >= off) ? lds[t - off] : 0;
        __syncthreads();
        lds[t] += x;
        __syncthreads();
    }
    if (t < nb) bsum[t] = lds[t] - s;   // exclusive
}

__global__ void scan3_kernel(int* __restrict__ rsp, int* __restrict__ cursor,
                             const int* __restrict__ bsum,
                             const int* __restrict__ cnt,
                             ushort* __restrict__ esrc, int n) {
    int i = blockIdx.x * blockDim.x + threadIdx.x;
    if (i >= n) return;
    int v = rsp[i] + bsum[i >> 10];   // >>10 == /SCAN_IPB
    rsp[i] = v;
    cursor[i] = v + 1;                // slot v holds the self-edge
    esrc[v] = (ushort)i;              // self-loop as a real edge
    int ci = cnt[i];
    int pc = (ci + 8) & ~7;
    for (int p = v + 1 + ci; p < v + pc; p++) esrc[p] = (ushort)n;  // pads
    if (i == n - 1) rsp[n] = v + pc;
}

// XCD-partitioned CSR fill; grid = 8 partitions x 256 blocks (full machine)
__global__ __launch_bounds__(256) void fill_kernel(
    const int* __restrict__ src, const int* __restrict__ dst,
    int* __restrict__ cursor, ushort* __restrict__ esrc, int E, int n) {
    int part = blockIdx.x & 7;
    int npp = (n + 7) >> 3;
    int lo = part * npp;
    int hi = min(n, lo + npp);
    int stride = (gridDim.x >> 3) * blockDim.x;
    for (int e = (blockIdx.x >> 3) * blockDim.x + threadIdx.x; e < E; e += stride) {
        int d = dst[e];
        if (d >= lo && d < hi) {
            int p = atomicAdd(&cursor[d], 1);
            esrc[p] = (ushort)src[e];
        }
    }
}

// ---------------------------------------------------------------- MFMA GEMM v3
// C = relu?(A) @ W, bf16 hi/lo split. Wave = 64 rows x 4 N-tiles: per k0,
// 4 A-frags (hi/lo) loaded once, each B hi/lo pair feeds 12 MFMAs.
// C chunk-major with pitch (n_rows+1), rows PRE-SCALED by dis[row].
template <bool RELU_IN>
__global__ __launch_bounds__(256, 2) void gemm_mfma(
    const float* __restrict__ A, const ushort* __restrict__ Bthi,
    const ushort* __restrict__ Btlo, const float* __restrict__ dis,
    float* __restrict__ C, int n_rows) {
    const int tid = threadIdx.x;
    const int bm0 = blockIdx.x * 256;        // block covers 256 rows
    const int wv = tid >> 6;
    const int lane = tid & 63;
    const int col = lane & 15;     // A row-in-frag / B col / C col
    const int quad = lane >> 4;    // k-block for A/B; row-quad for C
    const int rbase = bm0 + wv * 64 + col;   // wave rows: rbase + m*16
    const int ntBase = blockIdx.y * 4;

    f32x4 acc[4][4];   // [m][nt]
#pragma unroll
    for (int m = 0; m < 4; m++)
#pragma unroll
        for (int t = 0; t < 4; t++) acc[m][t] = (f32x4){0.f, 0.f, 0.f, 0.f};

#pragma unroll
    for (int k0 = 0; k0 < 4; k0++) {
        const int kb = k0 * 32 + quad * 8;
        bf16x8 ah[4], al[4];
#pragma unroll
        for (int m = 0; m < 4; m++) {
            int arow = rbase + m * 16;
            bool av = (arow < n_rows);
            const float* __restrict__ Ap = A + (size_t)arow * CH + kb;
            float4 f0 = av ? *(const float4*)Ap       : make_float4(0.f, 0.f, 0.f, 0.f);
            float4 f1 = av ? *(const float4*)(Ap + 4) : make_float4(0.f, 0.f, 0.f, 0.f);
            if (RELU_IN) {
                f0.x = fmaxf(f0.x, 0.f); f0.y = fmaxf(f0.y, 0.f);
                f0.z = fmaxf(f0.z, 0.f); f0.w = fmaxf(f0.w, 0.f);
                f1.x = fmaxf(f1.x, 0.f); f1.y = fmaxf(f1.y, 0.f);
                f1.z = fmaxf(f1.z, 0.f); f1.w = fmaxf(f1.w, 0.f);
            }
            float fa[8] = {f0.x, f0.y, f0.z, f0.w, f1.x, f1.y, f1.z, f1.w};
#pragma unroll
            for (int j = 0; j < 8; j++) {
                ushort h = f2bf(fa[j]);
                ah[m][j] = (short)h;
                al[m][j] = (short)f2bf(fa[j] - bf2f(h));
            }
        }
#pragma unroll
        for (int t = 0; t < 4; t++) {
            const int boff = ((ntBase + t) * 16 + col) * CH + kb;
            bf16x8 bh = *(const bf16x8*)&Bthi[boff];
            bf16x8 bl = *(const bf16x8*)&Btlo[boff];
#pragma unroll
            for (int m = 0; m < 4; m++) {
                acc[m][t] = __builtin_amdgcn_mfma_f32_16x16x32_bf16(ah[m], bh, acc[m][t], 0, 0, 0);
                acc[m][t] = __builtin_amdgcn_mfma_f32_16x16x32_bf16(ah[m], bl, acc[m][t], 0, 0, 0);
                acc[m][t] = __builtin_amdgcn_mfma_f32_16x16x32_bf16(al[m], bh, acc[m][t], 0, 0, 0);
            }
        }
    }

    // epilogue: C/D layout col=lane&15, row=quad*4+reg (m89-verified)
#pragma unroll
    for (int m = 0; m < 4; m++) {
#pragma unroll
        for (int reg = 0; reg < 4; reg++) {
            int gr = bm0 + wv * 64 + m * 16 + quad * 4 + reg;
            if (gr < n_rows) {
                float d = dis[gr];
#pragma unroll
                for (int t = 0; t < 4; t++) {
                    int nt = ntBase + t;
                    C[((size_t)nt * (n_rows + 1) + gr) * CHK + col] = acc[m][t][reg] * d;
                }
            }
        }
    }
}

// ---------------------------------------------------------------- CSR gather
// wave = (16 nodes, 1 chunk); chunk = blockIdx%8 pins the 3.2MB slice/XCD.
// Edge lists padded to x8 (pads -> zero row n). Lane = (g=lane>>2 node slot,
// q=lane&3 float4 of the 64B row). Per 8-edge iter: two broadcast ushort4
// index loads + 8 independent h-row loads.
__global__ __launch_bounds__(256) void gather_kernel(
    const int* __restrict__ rsp, const ushort* __restrict__ esrc,
    const float* __restrict__ dis, const float* __restrict__ hC,
    const float* __restrict__ bias, float* __restrict__ out, int n) {
    int c = blockIdx.x & 7;
    int wv = threadIdx.x >> 6;
    int lane = threadIdx.x & 63;
    int g = lane >> 2;    // node slot 0..15
    int q = lane & 3;     // float4 within the 16-channel row
    int i = (blockIdx.x >> 3) * 64 + wv * 16 + g;
    bool valid = (i < n);
    int iw = valid ? i : 0;
    const float4* __restrict__ h4 = (const float4*)(hC + (size_t)c * (n + 1) * CHK);

    int beg = valid ? rsp[iw] : 0;
    int end = valid ? rsp[iw + 1] : 0;
    float4 acc = make_float4(0.f, 0.f, 0.f, 0.f);
    for (int j = beg; j < end; j += 8) {   // beg/end are multiples of 8
        ushort4 e0 = *(const ushort4*)&esrc[j];
        ushort4 e1 = *(const ushort4*)&esrc[j + 4];
        float4 v0 = h4[(size_t)e0.x * 4 + q];
        float4 v1 = h4[(size_t)e0.y * 4 + q];
        float4 v2 = h4[(size_t)e0.z * 4 + q];
        float4 v3 = h4[(size_t)e0.w * 4 + q];
        float4 v4 = h4[(size_t)e1.x * 4 + q];
        float4 v5 = h4[(size_t)e1.y * 4 + q];
        float4 v6 = h4[(size_t)e1.z * 4 + q];
        float4 v7 = h4[(size_t)e1.w * 4 + q];
        acc.x += v0.x; acc.y += v0.y; acc.z += v0.z; acc.w += v0.w;
        acc.x += v1.x; acc.y += v1.y; acc.z += v1.z; acc.w += v1.w;
        acc.x += v2.x; acc.y += v2.y; acc.z += v2.z; acc.w += v2.w;
        acc.x += v3.x; acc.y += v3.y; acc.z += v3.z; acc.w += v3.w;
        acc.x += v4.x; acc.y += v4.y; acc.z += v4.z; acc.w += v4.w;
        acc.x += v5.x; acc.y += v5.y; acc.z += v5.z; acc.w += v5.w;
        acc.x += v6.x; acc.y += v6.y; acc.z += v6.z; acc.w += v6.w;
        acc.x += v7.x; acc.y += v7.y; acc.z += v7.z; acc.w += v7.w;
    }
    if (valid) {
        float di = dis[iw];
        float4 bv = ((const float4*)bias)[c * 4 + q];
        float4 o;
        o.x = bv.x + di * acc.x;
        o.y = bv.y + di * acc.y;
        o.z = bv.z + di * acc.z;
        o.w = bv.w + di * acc.w;
        ((float4*)out)[(size_t)iw * 32 + c * 4 + q] = o;
    }
}

// ---------------------------------------------------------------- head
__global__ __launch_bounds__(256) void head_kernel(
    const float* __restrict__ A, const float* __restrict__ Wh,
    const float* __restrict__ bh, float* __restrict__ out, int n) {
    __shared__ float Ws[CH * NCLS];
    __shared__ float As[16][129];
    const int tid = threadIdx.x;
    const int n0 = blockIdx.x * 16;
#pragma unroll
    for (int i = 0; i < 8; i++) {
        int l = tid + i * 256;
        Ws[l] = Wh[l];
    }
#pragma unroll
    for (int i = 0; i < 8; i++) {
        int l = tid + i * 256;
        int r = l >> 7, c = l & 127;
        int gr = n0 + r;
        As[r][c] = (gr < n) ? fmaxf(A[(size_t)gr * CH + c], 0.0f) : 0.0f;
    }
    __syncthreads();
    int r = tid >> 4, c = tid & 15;
    float acc = bh[c];
#pragma unroll
    for (int k = 0; k < CH; k++) acc = fmaf(As[r][k], Ws[k * NCLS + c], acc);
    int gr = n0 + r;
    if (gr < n) out[(size_t)gr * NCLS + c] = acc;
}

// ---------------------------------------------------------------- launch
extern "C" void kernel_launch(void* const* d_in, const int* in_sizes, int n_in,
                              void* d_out, int out_size, void* d_ws, size_t ws_size,
                              hipStream_t stream) {
    const float* x  = (const float*)d_in[0];
    const int*   ei = (const int*)d_in[1];
    const float* W1 = (const float*)d_in[2];
    const float* b1 = (const float*)d_in[3];
    const float* W2 = (const float*)d_in[4];
    const float* b2 = (const float*)d_in[5];
    const float* Wh = (const float*)d_in[6];
    const float* bh = (const float*)d_in[7];
    float* out = (float*)d_out;

    const int n = in_sizes[0] / CH;   // 50000
    const int E = in_sizes[1] / 2;    // 800000
    const int* src = ei;
    const int* dst = ei + E;

    // workspace layout
    ushort* w1hi = (ushort*)d_ws;                    // 16384 each
    ushort* w1lo = w1hi + CH * CH;
    ushort* w2hi = w1lo + CH * CH;
    ushort* w2lo = w2hi + CH * CH;
    float* dis  = (float*)(w2lo + CH * CH);          // n
    float* bufA = dis + n;                           // (n+1)*128 chunk-major h'
    float* bufB = bufA + (size_t)(n + 1) * CH;       // n*128 row-major
    int* cnt    = (int*)(bufB + (size_t)n * CH);     // n
    int* rsp    = cnt + n;                           // n+1 (padded CSR starts)
    int* cursor = rsp + n + 1;                       // n
    int* bsum   = cursor + n;                        // up to 256
    ushort* esrc = (ushort*)(bsum + 256);            // <= E + 8n padded edges

    const int B = 256;
    const int nb_scan = (n + SCAN_IPB - 1) / SCAN_IPB;   // 49
    const int nbz = (n + B - 1) / B;                     // cnt-zero blocks
    const int partGrid = 2048;  // 8 partitions x 256 blocks = 8192 waves (100%)

    // ---- prep + CSR build
    prep_kernel<<<128 + nbz + 1, B, 0, stream>>>(W1, W2, w1hi, w1lo, w2hi, w2lo,
                                                 cnt, bufA, n, nbz);
    count_kernel<<<partGrid, B, 0, stream>>>(dst, cnt, E, n);
    scan1_kernel<<<nb_scan, B, 0, stream>>>(cnt, rsp, bsum, dis, n);
    scan2_kernel<<<1, B, 0, stream>>>(bsum, nb_scan);
    scan3_kernel<<<(n + B - 1) / B, B, 0, stream>>>(rsp, cursor, bsum, cnt, esrc, n);
    fill_kernel<<<partGrid, B, 0, stream>>>(src, dst, cursor, esrc, E, n);

    const dim3 gemmGrid((n + 255) / 256, 2);
    const int gatherGrid = NCHUNK * ((n + 63) / 64);   // 64 nodes/block/chunk

    // layer 1
    gemm_mfma<false><<<gemmGrid, B, 0, stream>>>(x, w1hi, w1lo, dis, bufA, n);
    gather_kernel<<<gatherGrid, B, 0, stream>>>(rsp, esrc, dis, bufA, b1, bufB, n);
    // layer 2
    gemm_mfma<true><<<gemmGrid, B, 0, stream>>>(bufB, w2hi, w2lo, dis, bufA, n);
    gather_kernel<<<gatherGrid, B, 0, stream>>>(rsp, esrc, dis, bufA, b2, bufB, n);
    // head
    head_kernel<<<(n + 15) / 16, B, 0, stream>>>(bufB, Wh, bh, out, n);
}

// Round 14
// 313.876 us; speedup vs baseline: 1.6706x; 1.0079x over previous
//
#include <hip/hip_runtime.h>

#define CH 128
#define NCLS 16
#define CHK 16          // channels per chunk
#define NCHUNK 8        // 8 chunks of 16 == 128 channels, one per XCD
#define SCAN_IPB 1024   // items per block in scan pass 1

typedef __attribute__((ext_vector_type(8))) short bf16x8;
typedef __attribute__((ext_vector_type(4))) float f32x4;

__device__ inline ushort f2bf(float f) {        // RTNE fp32 -> bf16 bits
    unsigned u = __float_as_uint(f);
    unsigned r = u + 0x7fffu + ((u >> 16) & 1u);
    return (ushort)(r >> 16);
}
__device__ inline float bf2f(ushort b) {
    return __uint_as_float(((unsigned)b) << 16);
}

// ---------------------------------------------------------------- prep (fused)
__global__ __launch_bounds__(256) void prep_kernel(
    const float* __restrict__ W1, const float* __restrict__ W2,
    ushort* __restrict__ w1hi, ushort* __restrict__ w1lo,
    ushort* __restrict__ w2hi, ushort* __restrict__ w2lo,
    int* __restrict__ cnt, float* __restrict__ bufA, int n, int nbz) {
    int b = blockIdx.x, tid = threadIdx.x;
    if (b < 128) {
        const float* W = (b < 64) ? W1 : W2;
        ushort* Whi = (b < 64) ? w1hi : w2hi;
        ushort* Wlo = (b < 64) ? w1lo : w2lo;
        int t = ((b & 63) << 8) + tid;
        int k = t >> 7, nn = t & 127;
        float v = W[t];
        ushort h = f2bf(v);
        Whi[nn * CH + k] = h;
        Wlo[nn * CH + k] = f2bf(v - bf2f(h));
    } else if (b < 128 + nbz) {
        int i = (b - 128) * 256 + tid;
        if (i < n) cnt[i] = 0;
    } else {
        if (tid < NCHUNK * CHK) {
            int c = tid >> 4, ch = tid & 15;
            bufA[((size_t)c * (n + 1) + n) * CHK + ch] = 0.0f;
        }
    }
}

// XCD-partitioned degree count; grid = 8 partitions x 256 blocks (full machine)
__global__ __launch_bounds__(256) void count_kernel(
    const int* __restrict__ dst, int* __restrict__ cnt, int E, int n) {
    int part = blockIdx.x & 7;
    int npp = (n + 7) >> 3;
    int lo = part * npp;
    int hi = min(n, lo + npp);
    int stride = (gridDim.x >> 3) * blockDim.x;
    for (int e = (blockIdx.x >> 3) * blockDim.x + threadIdx.x; e < E; e += stride) {
        int d = dst[e];
        if (d >= lo && d < hi) atomicAdd(&cnt[d], 1);
    }
}

// ---------------------------------------------------------------- scan (CSR)
__global__ __launch_bounds__(256) void scan1_kernel(
    const int* __restrict__ cnt, int* __restrict__ rsp,
    int* __restrict__ bsum, float* __restrict__ dis, int n) {
    __shared__ int lds[256];
    int t = threadIdx.x, b = blockIdx.x;
    int base = b * SCAN_IPB + t * 4;
    int v[4];
    int s = 0;
#pragma unroll
    for (int k = 0; k < 4; k++) {
        if (base + k < n) {
            int c = cnt[base + k];
            v[k] = (c + 8) & ~7;        // round8(c+1)
            dis[base + k] = rsqrtf((float)c + 1.0f);
        } else v[k] = 0;
        s += v[k];
    }
    lds[t] = s;
    __syncthreads();
    for (int off = 1; off < 256; off <<= 1) {
        int x = (t >= off) ? lds[t - off] : 0;
        __syncthreads();
        lds[t] += x;
        __syncthreads();
    }
    int incl = lds[t];
    int run = incl - s;   // exclusive across threads
#pragma unroll
    for (int k = 0; k < 4; k++) {
        if (base + k < n) rsp[base + k] = run;
        run += v[k];
    }
    if (t == 255) bsum[b] = incl;
}

__global__ __launch_bounds__(256) void scan2_kernel(int* __restrict__ bsum, int nb) {
    __shared__ int lds[256];
    int t = threadIdx.x;
    int s = (t < nb) ? bsum[t] : 0;
    lds[t] = s;
    __syncthreads();
    for (int off = 1; off < 256; off <<= 1) {
        int x = (t >= off) ? lds[t - off] : 0;
        __syncthreads();
        lds[t] += x;
        __syncthreads();
    }
    if (t < nb) bsum[t] = lds[t] - s;   // exclusive
}

__global__ void scan3_kernel(int* __restrict__ rsp, int* __restrict__ cursor,
                             const int* __restrict__ bsum,
                             const int* __restrict__ cnt,
                             ushort* __restrict__ esrc, int n) {
    int i = blockIdx.x * blockDim.x + threadIdx.x;
    if (i >= n) return;
    int v = rsp[i] + bsum[i >> 10];   // >>10 == /SCAN_IPB
    rsp[i] = v;
    cursor[i] = v + 1;                // slot v holds the self-edge
    esrc[v] = (ushort)i;              // self-loop as a real edge
    int ci = cnt[i];
    int pc = (ci + 8) & ~7;
    for (int p = v + 1 + ci; p < v + pc; p++) esrc[p] = (ushort)n;  // pads
    if (i == n - 1) rsp[n] = v + pc;
}

// XCD-partitioned CSR fill; grid = 8 partitions x 256 blocks (full machine)
__global__ __launch_bounds__(256) void fill_kernel(
    const int* __restrict__ src, const int* __restrict__ dst,
    int* __restrict__ cursor, ushort* __restrict__ esrc, int E, int n) {
    int part = blockIdx.x & 7;
    int npp = (n + 7) >> 3;
    int lo = part * npp;
    int hi = min(n, lo + npp);
    int stride = (gridDim.x >> 3) * blockDim.x;
    for (int e = (blockIdx.x >> 3) * blockDim.x + threadIdx.x; e < E; e += stride) {
        int d = dst[e];
        if (d >= lo && d < hi) {
            int p = atomicAdd(&cursor[d], 1);
            esrc[p] = (ushort)src[e];
        }
    }
}

// ---------------------------------------------------------------- MFMA GEMM v3
// C = relu?(A) @ W, bf16 hi/lo split. Wave = 64 rows x 4 N-tiles: per k0,
// 4 A-frags (hi/lo) loaded once, each B hi/lo pair feeds 12 MFMAs.
// C chunk-major with pitch (n_rows+1), rows PRE-SCALED by dis[row].
template <bool RELU_IN>
__global__ __launch_bounds__(256, 2) void gemm_mfma(
    const float* __restrict__ A, const ushort* __restrict__ Bthi,
    const ushort* __restrict__ Btlo, const float* __restrict__ dis,
    float* __restrict__ C, int n_rows) {
    const int tid = threadIdx.x;
    const int bm0 = blockIdx.x * 256;        // block covers 256 rows
    const int wv = tid >> 6;
    const int lane = tid & 63;
    const int col = lane & 15;     // A row-in-frag / B col / C col
    const int quad = lane >> 4;    // k-block for A/B; row-quad for C
    const int rbase = bm0 + wv * 64 + col;   // wave rows: rbase + m*16
    const int ntBase = blockIdx.y * 4;

    f32x4 acc[4][4];   // [m][nt]
#pragma unroll
    for (int m = 0; m < 4; m++)
#pragma unroll
        for (int t = 0; t < 4; t++) acc[m][t] = (f32x4){0.f, 0.f, 0.f, 0.f};

#pragma unroll
    for (int k0 = 0; k0 < 4; k0++) {
        const int kb = k0 * 32 + quad * 8;
        bf16x8 ah[4], al[4];
#pragma unroll
        for (int m = 0; m < 4; m++) {
            int arow = rbase + m * 16;
            bool av = (arow < n_rows);
            const float* __restrict__ Ap = A + (size_t)arow * CH + kb;
            float4 f0 = av ? *(const float4*)Ap       : make_float4(0.f, 0.f, 0.f, 0.f);
            float4 f1 = av ? *(const float4*)(Ap + 4) : make_float4(0.f, 0.f, 0.f, 0.f);
            if (RELU_IN) {
                f0.x = fmaxf(f0.x, 0.f); f0.y = fmaxf(f0.y, 0.f);
                f0.z = fmaxf(f0.z, 0.f); f0.w = fmaxf(f0.w, 0.f);
                f1.x = fmaxf(f1.x, 0.f); f1.y = fmaxf(f1.y, 0.f);
                f1.z = fmaxf(f1.z, 0.f); f1.w = fmaxf(f1.w, 0.f);
            }
            float fa[8] = {f0.x, f0.y, f0.z, f0.w, f1.x, f1.y, f1.z, f1.w};
#pragma unroll
            for (int j = 0; j < 8; j++) {
                ushort h = f2bf(fa[j]);
                ah[m][j] = (short)h;
                al[m][j] = (short)f2bf(fa[j] - bf2f(h));
            }
        }
#pragma unroll
        for (int t = 0; t < 4; t++) {
            const int boff = ((ntBase + t) * 16 + col) * CH + kb;
            bf16x8 bh = *(const bf16x8*)&Bthi[boff];
            bf16x8 bl = *(const bf16x8*)&Btlo[boff];
#pragma unroll
            for (int m = 0; m < 4; m++) {
                acc[m][t] = __builtin_amdgcn_mfma_f32_16x16x32_bf16(ah[m], bh, acc[m][t], 0, 0, 0);
                acc[m][t] = __builtin_amdgcn_mfma_f32_16x16x32_bf16(ah[m], bl, acc[m][t], 0, 0, 0);
                acc[m][t] = __builtin_amdgcn_mfma_f32_16x16x32_bf16(al[m], bh, acc[m][t], 0, 0, 0);
            }
        }
    }

    // epilogue: C/D layout col=lane&15, row=quad*4+reg (m89-verified)
#pragma unroll
    for (int m = 0; m < 4; m++) {
#pragma unroll
        for (int reg = 0; reg < 4; reg++) {
            int gr = bm0 + wv * 64 + m * 16 + quad * 4 + reg;
            if (gr < n_rows) {
                float d = dis[gr];
#pragma unroll
                for (int t = 0; t < 4; t++) {
                    int nt = ntBase + t;
                    C[((size_t)nt * (n_rows + 1) + gr) * CHK + col] = acc[m][t][reg] * d;
                }
            }
        }
    }
}

// ---------------------------------------------------------------- CSR gather
// wave = (16 nodes, 1 chunk); chunk = blockIdx%8 pins the 3.2MB slice/XCD.
// NEW: (a) each block linearly pre-warms its 4KB share of the chunk slice --
// converts the 25.6MB random-order HBM first-touch into sequential fetch;
// (b) out-stores are NON-TEMPORAL so the 3.2MB/XCD write stream doesn't
// evict the L2-resident slice (which would force random re-fetches).
__global__ __launch_bounds__(256) void gather_kernel(
    const int* __restrict__ rsp, const ushort* __restrict__ esrc,
    const float* __restrict__ dis, const float* __restrict__ hC,
    const float* __restrict__ bias, float* __restrict__ out, int n) {
    int c = blockIdx.x & 7;
    int wv = threadIdx.x >> 6;
    int lane = threadIdx.x & 63;
    int g = lane >> 2;    // node slot 0..15
    int q = lane & 3;     // float4 within the 16-channel row
    int i = (blockIdx.x >> 3) * 64 + wv * 16 + g;
    bool valid = (i < n);
    int iw = valid ? i : 0;
    const float4* __restrict__ h4 = (const float4*)(hC + (size_t)c * (n + 1) * CHK);

    // sequential L2 pre-warm: one float4 per thread covers the slice
    float warm = 0.f;
    {
        int nblk = (n + 63) >> 6;                       // blocks per chunk
        size_t p = (size_t)(blockIdx.x >> 3) * 256 + threadIdx.x;
        size_t sliceF4 = ((size_t)(n + 1) * CHK) >> 2;  // float4 count
        for (; p < sliceF4; p += (size_t)nblk * 256) {
            float4 v = h4[p];
            warm += v.x + v.y + v.z + v.w;
        }
    }

    int beg = valid ? rsp[iw] : 0;
    int end = valid ? rsp[iw + 1] : 0;
    float4 acc = make_float4(0.f, 0.f, 0.f, 0.f);
    for (int j = beg; j < end; j += 8) {   // beg/end are multiples of 8
        ushort4 e0 = *(const ushort4*)&esrc[j];
        ushort4 e1 = *(const ushort4*)&esrc[j + 4];
        float4 v0 = h4[(size_t)e0.x * 4 + q];
        float4 v1 = h4[(size_t)e0.y * 4 + q];
        float4 v2 = h4[(size_t)e0.z * 4 + q];
        float4 v3 = h4[(size_t)e0.w * 4 + q];
        float4 v4 = h4[(size_t)e1.x * 4 + q];
        float4 v5 = h4[(size_t)e1.y * 4 + q];
        float4 v6 = h4[(size_t)e1.z * 4 + q];
        float4 v7 = h4[(size_t)e1.w * 4 + q];
        acc.x += v0.x; acc.y += v0.y; acc.z += v0.z; acc.w += v0.w;
        acc.x += v1.x; acc.y += v1.y; acc.z += v1.z; acc.w += v1.w;
        acc.x += v2.x; acc.y += v2.y; acc.z += v2.z; acc.w += v2.w;
        acc.x += v3.x; acc.y += v3.y; acc.z += v3.z; acc.w += v3.w;
        acc.x += v4.x; acc.y += v4.y; acc.z += v4.z; acc.w += v4.w;
        acc.x += v5.x; acc.y += v5.y; acc.z += v5.z; acc.w += v5.w;
        acc.x += v6.x; acc.y += v6.y; acc.z += v6.z; acc.w += v6.w;
        acc.x += v7.x; acc.y += v7.y; acc.z += v7.z; acc.w += v7.w;
    }
    // keep the warm loads alive (cannot be DCE'd)
    __asm__ volatile("" : : "v"(warm));
    if (valid) {
        float di = dis[iw];
        float4 bv = ((const float4*)bias)[c * 4 + q];
        f32x4 o;
        o[0] = bv.x + di * acc.x;
        o[1] = bv.y + di * acc.y;
        o[2] = bv.z + di * acc.z;
        o[3] = bv.w + di * acc.w;
        __builtin_nontemporal_store(o, (f32x4*)&((float4*)out)[(size_t)iw * 32 + c * 4 + q]);
    }
}

// ---------------------------------------------------------------- head
__global__ __launch_bounds__(256) void head_kernel(
    const float* __restrict__ A, const float* __restrict__ Wh,
    const float* __restrict__ bh, float* __restrict__ out, int n) {
    __shared__ float Ws[CH * NCLS];
    __shared__ float As[16][129];
    const int tid = threadIdx.x;
    const int n0 = blockIdx.x * 16;
#pragma unroll
    for (int i = 0; i < 8; i++) {
        int l = tid + i * 256;
        Ws[l] = Wh[l];
    }
#pragma unroll
    for (int i = 0; i < 8; i++) {
        int l = tid + i * 256;
        int r = l >> 7, c = l & 127;
        int gr = n0 + r;
        As[r][c] = (gr < n) ? fmaxf(A[(size_t)gr * CH + c], 0.0f) : 0.0f;
    }
    __syncthreads();
    int r = tid >> 4, c = tid & 15;
    float acc = bh[c];
#pragma unroll
    for (int k = 0; k < CH; k++) acc = fmaf(As[r][k], Ws[k * NCLS + c], acc);
    int gr = n0 + r;
    if (gr < n) out[(size_t)gr * NCLS + c] = acc;
}

// ---------------------------------------------------------------- launch
extern "C" void kernel_launch(void* const* d_in, const int* in_sizes, int n_in,
                              void* d_out, int out_size, void* d_ws, size_t ws_size,
                              hipStream_t stream) {
    const float* x  = (const float*)d_in[0];
    const int*   ei = (const int*)d_in[1];
    const float* W1 = (const float*)d_in[2];
    const float* b1 = (const float*)d_in[3];
    const float* W2 = (const float*)d_in[4];
    const float* b2 = (const float*)d_in[5];
    const float* Wh = (const float*)d_in[6];
    const float* bh = (const float*)d_in[7];
    float* out = (float*)d_out;

    const int n = in_sizes[0] / CH;   // 50000
    const int E = in_sizes[1] / 2;    // 800000
    const int* src = ei;
    const int* dst = ei + E;

    // workspace layout
    ushort* w1hi = (ushort*)d_ws;                    // 16384 each
    ushort* w1lo = w1hi + CH * CH;
    ushort* w2hi = w1lo + CH * CH;
    ushort* w2lo = w2hi + CH * CH;
    float* dis  = (float*)(w2lo + CH * CH);          // n
    float* bufA = dis + n;                           // (n+1)*128 chunk-major h'
    float* bufB = bufA + (size_t)(n + 1) * CH;       // n*128 row-major
    int* cnt    = (int*)(bufB + (size_t)n * CH);     // n
    int* rsp    = cnt + n;                           // n+1 (padded CSR starts)
    int* cursor = rsp + n + 1;                       // n
    int* bsum   = cursor + n;                        // up to 256
    ushort* esrc = (ushort*)(bsum + 256);            // <= E + 8n padded edges

    const int B = 256;
    const int nb_scan = (n + SCAN_IPB - 1) / SCAN_IPB;   // 49
    const int nbz = (n + B - 1) / B;                     // cnt-zero blocks
    const int partGrid = 2048;  // 8 partitions x 256 blocks = 8192 waves (100%)

    // ---- prep + CSR build
    prep_kernel<<<128 + nbz + 1, B, 0, stream>>>(W1, W2, w1hi, w1lo, w2hi, w2lo,
                                                 cnt, bufA, n, nbz);
    count_kernel<<<partGrid, B, 0, stream>>>(dst, cnt, E, n);
    scan1_kernel<<<nb_scan, B, 0, stream>>>(cnt, rsp, bsum, dis, n);
    scan2_kernel<<<1, B, 0, stream>>>(bsum, nb_scan);
    scan3_kernel<<<(n + B - 1) / B, B, 0, stream>>>(rsp, cursor, bsum, cnt, esrc, n);
    fill_kernel<<<partGrid, B, 0, stream>>>(src, dst, cursor, esrc, E, n);

    const dim3 gemmGrid((n + 255) / 256, 2);
    const int gatherGrid = NCHUNK * ((n + 63) / 64);   // 64 nodes/block/chunk

    // layer 1
    gemm_mfma<false><<<gemmGrid, B, 0, stream>>>(x, w1hi, w1lo, dis, bufA, n);
    gather_kernel<<<gatherGrid, B, 0, stream>>>(rsp, esrc, dis, bufA, b1, bufB, n);
    // layer 2
    gemm_mfma<true><<<gemmGrid, B, 0, stream>>>(bufB, w2hi, w2lo, dis, bufA, n);
    gather_kernel<<<gatherGrid, B, 0, stream>>>(rsp, esrc, dis, bufA, b2, bufB, n);
    // head
    head_kernel<<<(n + 15) / 16, B, 0, stream>>>(bufB, Wh, bh, out, n);
}